// Round 1
// baseline (2197.125 us; speedup 1.0000x reference)
//
#include <hip/hip_runtime.h>
#include <hip/hip_bf16.h>
#include <math.h>

#define N_NODES 100000
#define N_EDGES 3200000
#define F_IN 128
#define HID 256
#define KCL 30
#define NT1 32

// scal layout: [0]=m, [1]=connectivity, [2..31]=colsum(30), [32..60]=svec(29)

// ---------- pass1: weighted degrees (col & row), edge counts per col, m ----------
__global__ __launch_bounds__(256) void k_pass1(const int* __restrict__ ei,
                                               const float* __restrict__ w,
                                               float* __restrict__ deg_w,
                                               float* __restrict__ degree,
                                               int* __restrict__ cnt,
                                               float* __restrict__ m_out) {
  int e = blockIdx.x * 256 + threadIdx.x;
  float wv = 0.f;
  if (e < N_EDGES) {
    int r = ei[e];
    int c = ei[N_EDGES + e];
    wv = w[e];
    atomicAdd(deg_w + c, wv);   // normalization degree: segment_sum over col
    atomicAdd(degree + r, wv);  // modularity degree:    segment_sum over row
    atomicAdd(cnt + c, 1);
  }
  #pragma unroll
  for (int o = 32; o > 0; o >>= 1) wv += __shfl_down(wv, o);
  __shared__ float ls[4];
  int lane = threadIdx.x & 63, wid = threadIdx.x >> 6;
  if (lane == 0) ls[wid] = wv;
  __syncthreads();
  if (threadIdx.x == 0) atomicAdd(m_out, ls[0] + ls[1] + ls[2] + ls[3]);
}

// ---------- dis = rsqrt(deg_w + 1)  (self-loop weight 1) ----------
__global__ __launch_bounds__(256) void k_dis(const float* __restrict__ deg_w,
                                             float* __restrict__ dis) {
  int n = blockIdx.x * 256 + threadIdx.x;
  if (n < N_NODES) dis[n] = rsqrtf(deg_w[n] + 1.f);
}

// ---------- single-block exclusive scan of cnt -> rowptr ----------
__global__ __launch_bounds__(1024) void k_scan(const int* __restrict__ cnt,
                                               int* __restrict__ rowptr) {
  __shared__ int wsum[16];
  __shared__ int s_carry;
  const int t = threadIdx.x;
  const int lane = t & 63, wid = t >> 6;
  if (t == 0) s_carry = 0;
  __syncthreads();
  for (int base = 0; base < N_NODES; base += 1024) {
    int i = base + t;
    int v = (i < N_NODES) ? cnt[i] : 0;
    int x = v;
    #pragma unroll
    for (int o = 1; o < 64; o <<= 1) {
      int y = __shfl_up(x, o);
      if (lane >= o) x += y;
    }
    if (lane == 63) wsum[wid] = x;
    __syncthreads();
    if (t < 16) {
      int s = wsum[t];
      #pragma unroll
      for (int o = 1; o < 16; o <<= 1) {
        int y = __shfl_up(s, o);
        if (t >= o) s += y;
      }
      wsum[t] = s;
    }
    __syncthreads();
    int excl = s_carry + (wid ? wsum[wid - 1] : 0) + x - v;
    if (i < N_NODES) rowptr[i] = excl;
    __syncthreads();
    if (t == 0) s_carry += wsum[15];
    __syncthreads();
  }
  if (t == 0) rowptr[N_NODES] = N_EDGES;
}

// ---------- scatter edges into CSR (keyed by col), precompute norm ----------
__global__ __launch_bounds__(256) void k_csrfill(const int* __restrict__ ei,
                                                 const float* __restrict__ w,
                                                 const float* __restrict__ dis,
                                                 const int* __restrict__ rowptr,
                                                 int* __restrict__ fill,
                                                 int* __restrict__ csr_src,
                                                 float* __restrict__ csr_norm) {
  int e = blockIdx.x * 256 + threadIdx.x;
  if (e >= N_EDGES) return;
  int r = ei[e], c = ei[N_EDGES + e];
  float nrm = dis[r] * w[e] * dis[c];
  int pos = rowptr[c] + atomicAdd(fill + c, 1);
  csr_src[pos] = r;
  csr_norm[pos] = nrm;
}

// ---------- layer-1 dual GEMM: hconv = x@Wc ; base1 = x@Wl + bl + bc + dis^2*hconv ----------
__global__ __launch_bounds__(256) void k_gemm1(const float* __restrict__ x,
                                               const float* __restrict__ Wc,
                                               const float* __restrict__ Wl,
                                               const float* __restrict__ bc,
                                               const float* __restrict__ bl,
                                               const float* __restrict__ dis,
                                               float* __restrict__ hconv,
                                               float* __restrict__ base1) {
  __shared__ float xsT[F_IN][NT1];   // 16 KB  [k][node]
  __shared__ float WcS[32][HID];     // 32 KB
  __shared__ float WlS[32][HID];     // 32 KB
  const int t = threadIdx.x;
  const int n0 = blockIdx.x * NT1;
  // stage x transposed: lane's node = t&31 (bank-conflict-free writes: bank = n%32)
  {
    int n = t & 31, kb = t >> 5;   // kb in 0..7
    const float* xr = x + (size_t)(n0 + n) * F_IN + kb * 16;
    #pragma unroll
    for (int j = 0; j < 16; ++j) xsT[kb * 16 + j][n] = xr[j];
  }
  float accC[NT1], accL[NT1];
  #pragma unroll
  for (int i = 0; i < NT1; ++i) { accC[i] = 0.f; accL[i] = 0.f; }
  const int c = t;  // output column, 0..255
  for (int kc = 0; kc < F_IN; kc += 32) {
    __syncthreads();
    const float4* Wc4 = (const float4*)(Wc + (size_t)kc * HID);
    const float4* Wl4 = (const float4*)(Wl + (size_t)kc * HID);
    #pragma unroll
    for (int i = 0; i < 8; ++i) {
      int idx = t + i * 256;          // 2048 float4 per 32xHID chunk
      int kk = idx >> 6, c4 = idx & 63;
      *((float4*)&WcS[kk][c4 * 4]) = Wc4[(size_t)kk * 64 + c4];
      *((float4*)&WlS[kk][c4 * 4]) = Wl4[(size_t)kk * 64 + c4];
    }
    __syncthreads();
    for (int kk = 0; kk < 32; ++kk) {
      float wc = WcS[kk][c], wl = WlS[kk][c];
      const float4* xv = (const float4*)&xsT[kc + kk][0];
      #pragma unroll
      for (int q = 0; q < 8; ++q) {
        float4 v = xv[q];
        accC[q * 4 + 0] += v.x * wc; accL[q * 4 + 0] += v.x * wl;
        accC[q * 4 + 1] += v.y * wc; accL[q * 4 + 1] += v.y * wl;
        accC[q * 4 + 2] += v.z * wc; accL[q * 4 + 2] += v.z * wl;
        accC[q * 4 + 3] += v.w * wc; accL[q * 4 + 3] += v.w * wl;
      }
    }
  }
  float bcv = bc[c], blv = bl[c];
  #pragma unroll
  for (int n = 0; n < NT1; ++n) {
    int gn = n0 + n;
    float d = dis[gn];
    float hc = accC[n];
    hconv[(size_t)gn * HID + c] = hc;
    base1[(size_t)gn * HID + c] = accL[n] + blv + bcv + d * d * hc;
  }
}

// ---------- layer-1 aggregation: h1 = relu(sum_e norm*hconv[src] + base1) in-place ----------
__global__ __launch_bounds__(256) void k_agg1(const int* __restrict__ rowptr,
                                              const int* __restrict__ csr_src,
                                              const float* __restrict__ csr_norm,
                                              const float* __restrict__ hconv,
                                              float* __restrict__ h1 /* = base1 */) {
  const int n = blockIdx.x;
  const int t = threadIdx.x;
  const int e0 = rowptr[n], e1 = rowptr[n + 1];
  __shared__ int s_src[256];
  __shared__ float s_nrm[256];
  float acc = 0.f;
  for (int jb = e0; jb < e1; jb += 256) {
    int cn = min(256, e1 - jb);
    __syncthreads();
    if (t < cn) { s_src[t] = csr_src[jb + t]; s_nrm[t] = csr_norm[jb + t]; }
    __syncthreads();
    int j = 0;
    for (; j + 4 <= cn; j += 4) {
      int s0 = s_src[j], s1 = s_src[j + 1], s2 = s_src[j + 2], s3 = s_src[j + 3];
      float v0 = hconv[(size_t)s0 * HID + t];
      float v1 = hconv[(size_t)s1 * HID + t];
      float v2 = hconv[(size_t)s2 * HID + t];
      float v3 = hconv[(size_t)s3 * HID + t];
      acc = fmaf(s_nrm[j], v0, acc);
      acc = fmaf(s_nrm[j + 1], v1, acc);
      acc = fmaf(s_nrm[j + 2], v2, acc);
      acc = fmaf(s_nrm[j + 3], v3, acc);
    }
    for (; j < cn; ++j) acc = fmaf(s_nrm[j], hconv[(size_t)s_src[j] * HID + t], acc);
  }
  float v = acc + h1[(size_t)n * HID + t];
  h1[(size_t)n * HID + t] = fmaxf(v, 0.f);
}

// ---------- layer-2 dual GEMM: hconv2 = h1@Wc2 ; base2 = h1@Wl2 + bl2 + bc2 + dis^2*hconv2 ----------
__global__ __launch_bounds__(256) void k_gemm2(const float* __restrict__ h1,
                                               const float* __restrict__ Wc,
                                               const float* __restrict__ Wl,
                                               const float* __restrict__ bc,
                                               const float* __restrict__ bl,
                                               const float* __restrict__ dis,
                                               float* __restrict__ hconv2,
                                               float* __restrict__ base2) {
  __shared__ float h1s[8][HID];     // 8 KB
  __shared__ float WcS[HID][32];    // 32 KB (padded to 32 cols)
  __shared__ float WlS[HID][32];    // 32 KB
  const int t = threadIdx.x;
  const int n0 = blockIdx.x * 8;
  for (int idx = t; idx < HID * 32; idx += 256) {
    int k = idx >> 5, c = idx & 31;
    float vc = 0.f, vl = 0.f;
    if (c < KCL) { vc = Wc[k * KCL + c]; vl = Wl[k * KCL + c]; }
    WcS[k][c] = vc; WlS[k][c] = vl;
  }
  {
    const float4* h4 = (const float4*)(h1 + (size_t)n0 * HID);
    #pragma unroll
    for (int i = 0; i < 2; ++i) {
      int idx = t + i * 256;        // 512 float4
      int n = idx >> 6, k4 = idx & 63;
      *((float4*)&h1s[n][k4 * 4]) = h4[(size_t)n * 64 + k4];
    }
  }
  __syncthreads();
  const int lane = t & 63;
  const int wid = t >> 6;
  const int half = lane >> 5;
  const int c = lane & 31;
  const int nl = wid * 2 + half;    // 0..7
  const int gn = n0 + nl;
  float accC = 0.f, accL = 0.f;
  #pragma unroll 4
  for (int k = 0; k < HID; ++k) {
    float h = h1s[nl][k];
    accC = fmaf(h, WcS[k][c], accC);
    accL = fmaf(h, WlS[k][c], accL);
  }
  if (c < KCL) {
    float d = dis[gn];
    hconv2[(size_t)gn * KCL + c] = accC;
    base2[(size_t)gn * KCL + c] = accL + bl[c] + bc[c] + d * d * accC;
  }
}

// ---------- layer-2 aggregation + softmax + clip + FX write + colsum/svec partials ----------
__global__ __launch_bounds__(256) void k_agg2(const int* __restrict__ rowptr,
                                              const int* __restrict__ csr_src,
                                              const float* __restrict__ csr_norm,
                                              const float* __restrict__ hconv2,
                                              const float* __restrict__ base2,
                                              const float* __restrict__ degree,
                                              float* __restrict__ FX,
                                              float* __restrict__ scal) {
  const int t = threadIdx.x;
  const int lane = t & 63, wid = t >> 6;
  const int half = lane >> 5, c = lane & 31;
  const int nwaves = gridDim.x * 4;
  const int gw = blockIdx.x * 4 + wid;
  float cs_acc = 0.f, s_acc = 0.f;
  for (int n = gw; n < N_NODES; n += nwaves) {
    int e0 = rowptr[n], e1 = rowptr[n + 1];
    float acc = 0.f;
    for (int j = e0 + half; j < e1; j += 2) {
      int src = csr_src[j];
      float nrm = csr_norm[j];
      if (c < KCL) acc = fmaf(nrm, hconv2[(size_t)src * KCL + c], acc);
    }
    acc += __shfl(acc, lane ^ 32);  // combine the two half-wave edge partitions
    float out = (c < KCL) ? acc + base2[(size_t)n * KCL + c] : -1e30f;
    float mx = out;
    #pragma unroll
    for (int o = 16; o > 0; o >>= 1) mx = fmaxf(mx, __shfl_xor(mx, o));
    float p = (c < KCL) ? __expf(out - mx) : 0.f;
    float sum = p;
    #pragma unroll
    for (int o = 16; o > 0; o >>= 1) sum += __shfl_xor(sum, o);
    float fx = p / sum;
    fx = fminf(fmaxf(fx, 1e-9f), 1.f - 1e-9f);
    if (half == 0 && c < KCL) FX[(size_t)n * KCL + c] = fx;
    float degv = degree[n];
    cs_acc += (c < KCL) ? fx : 0.f;
    s_acc += (c < KCL - 1) ? fx * degv : 0.f;
  }
  __shared__ float red_cs[4][32];
  __shared__ float red_s[4][32];
  if (half == 0) { red_cs[wid][c] = cs_acc; red_s[wid][c] = s_acc; }
  __syncthreads();
  if (t < 32) {
    float a = red_cs[0][t] + red_cs[1][t] + red_cs[2][t] + red_cs[3][t];
    float b = red_s[0][t] + red_s[1][t] + red_s[2][t] + red_s[3][t];
    if (t < KCL) atomicAdd(&scal[2 + t], a);
    if (t < KCL - 1) atomicAdd(&scal[32 + t], b);
  }
}

// ---------- modularity connectivity: sum_e w * dot(FX[r,:29], FX[c,:29]) ----------
__global__ __launch_bounds__(256) void k_conn(const int* __restrict__ ei,
                                              const float* __restrict__ w,
                                              const float* __restrict__ FX,
                                              float* __restrict__ conn) {
  int e = blockIdx.x * 256 + threadIdx.x;
  float val = 0.f;
  if (e < N_EDGES) {
    int r = ei[e], cc = ei[N_EDGES + e];
    const float2* fr = (const float2*)(FX + (size_t)r * KCL);
    const float2* fc = (const float2*)(FX + (size_t)cc * KCL);
    float dot = 0.f;
    #pragma unroll
    for (int k = 0; k < 14; ++k) {
      float2 a = fr[k], b = fc[k];
      dot += a.x * b.x + a.y * b.y;
    }
    dot += FX[(size_t)r * KCL + 28] * FX[(size_t)cc * KCL + 28];
    val = w[e] * dot;
  }
  #pragma unroll
  for (int o = 32; o > 0; o >>= 1) val += __shfl_down(val, o);
  __shared__ float ls[4];
  int lane = threadIdx.x & 63, wid = threadIdx.x >> 6;
  if (lane == 0) ls[wid] = val;
  __syncthreads();
  if (threadIdx.x == 0) atomicAdd(conn, ls[0] + ls[1] + ls[2] + ls[3]);
}

// ---------- final scalar loss ----------
__global__ void k_finalize(const float* __restrict__ scal, float* __restrict__ out_loss) {
  if (threadIdx.x == 0 && blockIdx.x == 0) {
    float m = scal[0], conn = scal[1];
    float ss = 0.f;
    for (int k = 0; k < KCL - 1; ++k) { float s = scal[32 + k]; ss += s * s; }
    float cs2 = 0.f;
    for (int k = 0; k < KCL; ++k) { float cv = scal[2 + k]; cs2 += cv * cv; }
    float avg = ss / (2.f * m);
    float modularity = -(conn - avg) / (2.f * m);
    float reg = sqrtf(cs2 + 1e-9f) * sqrtf((float)KCL) / (float)N_NODES - 1.f;
    out_loss[0] = modularity + 0.01f * reg;
  }
}

extern "C" void kernel_launch(void* const* d_in, const int* in_sizes, int n_in,
                              void* d_out, int out_size, void* d_ws, size_t ws_size,
                              hipStream_t stream) {
  const float* x   = (const float*)d_in[0];
  const int*   ei  = (const int*)d_in[1];
  const float* ea  = (const float*)d_in[2];
  const float* Wc1 = (const float*)d_in[3];
  const float* bc1 = (const float*)d_in[4];
  const float* Wl1 = (const float*)d_in[5];
  const float* bl1 = (const float*)d_in[6];
  const float* Wc2 = (const float*)d_in[7];
  const float* bc2 = (const float*)d_in[8];
  const float* Wl2 = (const float*)d_in[9];
  const float* bl2 = (const float*)d_in[10];
  float* out = (float*)d_out;

  float* ws = (float*)d_ws;
  size_t o = 0;
  float* deg_w  = ws + o; o += N_NODES;
  float* degree = ws + o; o += N_NODES;
  int*   cnt    = (int*)(ws + o); o += N_NODES;
  int*   fill   = (int*)(ws + o); o += N_NODES;
  float* scal   = ws + o; o += 64;
  size_t zero_floats = o;                       // everything above needs zeroing
  float* dis    = ws + o; o += N_NODES;
  int*   rowptr = (int*)(ws + o); o += N_NODES + 8;
  int*   csr_src= (int*)(ws + o); o += N_EDGES;
  float* csr_nrm= ws + o; o += N_EDGES;
  float* hconv  = ws + o; o += (size_t)N_NODES * HID;
  float* base1  = ws + o; o += (size_t)N_NODES * HID;  // becomes h1 in-place
  float* hconv2 = ws + o; o += (size_t)N_NODES * KCL;
  float* base2  = ws + o; o += (size_t)N_NODES * KCL;
  o += 64;  // slack for speculative over-reads
  if (ws_size < o * sizeof(float)) return;  // insufficient workspace — bail safely

  hipMemsetAsync(d_ws, 0, zero_floats * sizeof(float), stream);

  k_pass1<<<N_EDGES / 256, 256, 0, stream>>>(ei, ea, deg_w, degree, cnt, scal);
  k_dis<<<(N_NODES + 255) / 256, 256, 0, stream>>>(deg_w, dis);
  k_scan<<<1, 1024, 0, stream>>>(cnt, rowptr);
  k_csrfill<<<N_EDGES / 256, 256, 0, stream>>>(ei, ea, dis, rowptr, fill, csr_src, csr_nrm);
  k_gemm1<<<N_NODES / NT1, 256, 0, stream>>>(x, Wc1, Wl1, bc1, bl1, dis, hconv, base1);
  k_agg1<<<N_NODES, 256, 0, stream>>>(rowptr, csr_src, csr_nrm, hconv, base1);
  k_gemm2<<<N_NODES / 8, 256, 0, stream>>>(base1, Wc2, Wl2, bc2, bl2, dis, hconv2, base2);
  k_agg2<<<1024, 256, 0, stream>>>(rowptr, csr_src, csr_nrm, hconv2, base2, degree, out, scal);
  k_conn<<<N_EDGES / 256, 256, 0, stream>>>(ei, ea, out, scal + 1);
  k_finalize<<<1, 64, 0, stream>>>(scal, out + (size_t)N_NODES * KCL);
}

// Round 2
// 1772.012 us; speedup vs baseline: 1.2399x; 1.2399x over previous
//
#include <hip/hip_runtime.h>
#include <hip/hip_bf16.h>
#include <math.h>

#define N_NODES 100000
#define N_EDGES 3200000
#define F_IN 128
#define HID 256
#define KCL 30
#define NT1 32

typedef unsigned int uint;
typedef unsigned short ushort;

static __device__ __forceinline__ float bf2f(ushort u) {
  return __uint_as_float(((uint)u) << 16);
}
static __device__ __forceinline__ ushort f2bf(float f) {
  uint u = __float_as_uint(f);
  uint r = (u + 0x7FFF + ((u >> 16) & 1)) >> 16;   // round-to-nearest-even
  return (ushort)r;
}

// scal layout: [0]=m, [1]=connectivity, [2..31]=colsum(30), [32..60]=svec(29)

// ---------- pass1: weighted degrees (col & row), edge counts per col, m ----------
__global__ __launch_bounds__(256) void k_pass1(const int* __restrict__ ei,
                                               const float* __restrict__ w,
                                               float* __restrict__ deg_w,
                                               float* __restrict__ degree,
                                               int* __restrict__ cnt,
                                               float* __restrict__ m_out) {
  int e = blockIdx.x * 256 + threadIdx.x;
  float wv = 0.f;
  if (e < N_EDGES) {
    int r = ei[e];
    int c = ei[N_EDGES + e];
    wv = w[e];
    atomicAdd(deg_w + c, wv);   // normalization degree: segment_sum over col
    atomicAdd(degree + r, wv);  // modularity degree:    segment_sum over row
    atomicAdd(cnt + c, 1);
  }
  #pragma unroll
  for (int o = 32; o > 0; o >>= 1) wv += __shfl_down(wv, o);
  __shared__ float ls[4];
  int lane = threadIdx.x & 63, wid = threadIdx.x >> 6;
  if (lane == 0) ls[wid] = wv;
  __syncthreads();
  if (threadIdx.x == 0) atomicAdd(m_out, ls[0] + ls[1] + ls[2] + ls[3]);
}

// ---------- dis = rsqrt(deg_w + 1)  (self-loop weight 1) ----------
__global__ __launch_bounds__(256) void k_dis(const float* __restrict__ deg_w,
                                             float* __restrict__ dis) {
  int n = blockIdx.x * 256 + threadIdx.x;
  if (n < N_NODES) dis[n] = rsqrtf(deg_w[n] + 1.f);
}

// ---------- single-block exclusive scan of cnt -> rowptr ----------
__global__ __launch_bounds__(1024) void k_scan(const int* __restrict__ cnt,
                                               int* __restrict__ rowptr) {
  __shared__ int wsum[16];
  __shared__ int s_carry;
  const int t = threadIdx.x;
  const int lane = t & 63, wid = t >> 6;
  if (t == 0) s_carry = 0;
  __syncthreads();
  for (int base = 0; base < N_NODES; base += 1024) {
    int i = base + t;
    int v = (i < N_NODES) ? cnt[i] : 0;
    int x = v;
    #pragma unroll
    for (int o = 1; o < 64; o <<= 1) {
      int y = __shfl_up(x, o);
      if (lane >= o) x += y;
    }
    if (lane == 63) wsum[wid] = x;
    __syncthreads();
    if (t < 16) {
      int s = wsum[t];
      #pragma unroll
      for (int o = 1; o < 16; o <<= 1) {
        int y = __shfl_up(s, o);
        if (t >= o) s += y;
      }
      wsum[t] = s;
    }
    __syncthreads();
    int excl = s_carry + (wid ? wsum[wid - 1] : 0) + x - v;
    if (i < N_NODES) rowptr[i] = excl;
    __syncthreads();
    if (t == 0) s_carry += wsum[15];
    __syncthreads();
  }
  if (t == 0) rowptr[N_NODES] = N_EDGES;
}

// ---------- scatter edges into CSR (keyed by col), precompute norm ----------
__global__ __launch_bounds__(256) void k_csrfill(const int* __restrict__ ei,
                                                 const float* __restrict__ w,
                                                 const float* __restrict__ dis,
                                                 const int* __restrict__ rowptr,
                                                 int* __restrict__ fill,
                                                 int* __restrict__ csr_src,
                                                 float* __restrict__ csr_norm) {
  int e = blockIdx.x * 256 + threadIdx.x;
  if (e >= N_EDGES) return;
  int r = ei[e], c = ei[N_EDGES + e];
  float nrm = dis[r] * w[e] * dis[c];
  int pos = rowptr[c] + atomicAdd(fill + c, 1);
  csr_src[pos] = r;
  csr_norm[pos] = nrm;
}

// ---------- layer-1 dual GEMM: hconv(bf16) = x@Wc ; base1 = x@Wl + bl + bc + dis^2*hconv ----------
__global__ __launch_bounds__(256) void k_gemm1(const float* __restrict__ x,
                                               const float* __restrict__ Wc,
                                               const float* __restrict__ Wl,
                                               const float* __restrict__ bc,
                                               const float* __restrict__ bl,
                                               const float* __restrict__ dis,
                                               ushort* __restrict__ hconv_bf,
                                               float* __restrict__ base1) {
  __shared__ float xsT[F_IN][NT1];   // 16 KB  [k][node]
  __shared__ float WcS[32][HID];     // 32 KB
  __shared__ float WlS[32][HID];     // 32 KB
  const int t = threadIdx.x;
  const int n0 = blockIdx.x * NT1;
  {
    int n = t & 31, kb = t >> 5;   // kb in 0..7
    const float* xr = x + (size_t)(n0 + n) * F_IN + kb * 16;
    #pragma unroll
    for (int j = 0; j < 16; ++j) xsT[kb * 16 + j][n] = xr[j];
  }
  float accC[NT1], accL[NT1];
  #pragma unroll
  for (int i = 0; i < NT1; ++i) { accC[i] = 0.f; accL[i] = 0.f; }
  const int c = t;  // output column, 0..255
  for (int kc = 0; kc < F_IN; kc += 32) {
    __syncthreads();
    const float4* Wc4 = (const float4*)(Wc + (size_t)kc * HID);
    const float4* Wl4 = (const float4*)(Wl + (size_t)kc * HID);
    #pragma unroll
    for (int i = 0; i < 8; ++i) {
      int idx = t + i * 256;          // 2048 float4 per 32xHID chunk
      int kk = idx >> 6, c4 = idx & 63;
      *((float4*)&WcS[kk][c4 * 4]) = Wc4[(size_t)kk * 64 + c4];
      *((float4*)&WlS[kk][c4 * 4]) = Wl4[(size_t)kk * 64 + c4];
    }
    __syncthreads();
    for (int kk = 0; kk < 32; ++kk) {
      float wc = WcS[kk][c], wl = WlS[kk][c];
      const float4* xv = (const float4*)&xsT[kc + kk][0];
      #pragma unroll
      for (int q = 0; q < 8; ++q) {
        float4 v = xv[q];
        accC[q * 4 + 0] += v.x * wc; accL[q * 4 + 0] += v.x * wl;
        accC[q * 4 + 1] += v.y * wc; accL[q * 4 + 1] += v.y * wl;
        accC[q * 4 + 2] += v.z * wc; accL[q * 4 + 2] += v.z * wl;
        accC[q * 4 + 3] += v.w * wc; accL[q * 4 + 3] += v.w * wl;
      }
    }
  }
  float bcv = bc[c], blv = bl[c];
  #pragma unroll
  for (int n = 0; n < NT1; ++n) {
    int gn = n0 + n;
    float d = dis[gn];
    float hc = accC[n];
    hconv_bf[(size_t)gn * HID + c] = f2bf(hc);
    base1[(size_t)gn * HID + c] = accL[n] + blv + bcv + d * d * hc;
  }
}

// ---------- layer-1 aggregation: h1_bf = bf16(relu(sum_e norm*hconv[src] + base1)) ----------
// One block per node; 4 waves each take edges j%4==wid; lane reads ushort4 (cols 4l..4l+3).
__global__ __launch_bounds__(256) void k_agg1(const int* __restrict__ rowptr,
                                              const int* __restrict__ csr_src,
                                              const float* __restrict__ csr_norm,
                                              const ushort* __restrict__ hconv_bf,
                                              const float* __restrict__ base1,
                                              ushort* __restrict__ h1b) {
  const int n = blockIdx.x;
  const int t = threadIdx.x;
  const int lane = t & 63, wid = t >> 6;
  const int e0 = rowptr[n], e1 = rowptr[n + 1];
  __shared__ int s_src[256];
  __shared__ float s_nrm[256];
  __shared__ float red[4][256];
  float acc0 = 0.f, acc1 = 0.f, acc2 = 0.f, acc3 = 0.f;
  for (int jb = e0; jb < e1; jb += 256) {
    int cn = min(256, e1 - jb);
    __syncthreads();
    if (t < cn) { s_src[t] = csr_src[jb + t]; s_nrm[t] = csr_norm[jb + t]; }
    __syncthreads();
    int j = wid;
    for (; j + 4 < cn; j += 8) {
      int sA = s_src[j];         float nA = s_nrm[j];
      int sB = s_src[j + 4];     float nB = s_nrm[j + 4];
      ushort4 vA = *(const ushort4*)(hconv_bf + (size_t)sA * HID + lane * 4);
      ushort4 vB = *(const ushort4*)(hconv_bf + (size_t)sB * HID + lane * 4);
      acc0 = fmaf(nA, bf2f(vA.x), acc0); acc1 = fmaf(nA, bf2f(vA.y), acc1);
      acc2 = fmaf(nA, bf2f(vA.z), acc2); acc3 = fmaf(nA, bf2f(vA.w), acc3);
      acc0 = fmaf(nB, bf2f(vB.x), acc0); acc1 = fmaf(nB, bf2f(vB.y), acc1);
      acc2 = fmaf(nB, bf2f(vB.z), acc2); acc3 = fmaf(nB, bf2f(vB.w), acc3);
    }
    if (j < cn) {
      int sA = s_src[j]; float nA = s_nrm[j];
      ushort4 vA = *(const ushort4*)(hconv_bf + (size_t)sA * HID + lane * 4);
      acc0 = fmaf(nA, bf2f(vA.x), acc0); acc1 = fmaf(nA, bf2f(vA.y), acc1);
      acc2 = fmaf(nA, bf2f(vA.z), acc2); acc3 = fmaf(nA, bf2f(vA.w), acc3);
    }
  }
  __syncthreads();
  ((float4*)red[wid])[lane] = make_float4(acc0, acc1, acc2, acc3);
  __syncthreads();
  float v = red[0][t] + red[1][t] + red[2][t] + red[3][t] + base1[(size_t)n * HID + t];
  h1b[(size_t)n * HID + t] = f2bf(fmaxf(v, 0.f));
}

// ---------- layer-2 dual GEMM (register-blocked): hconv2 = h1@Wc2 ; base2 = h1@Wl2 + ... ----------
// Block = 64 nodes, 256 threads: thread (c = t&31, g = t>>5) computes 8 nodes x 1 col x 2 mats.
__global__ __launch_bounds__(256) void k_gemm2(const ushort* __restrict__ h1b,
                                               const float* __restrict__ Wc,
                                               const float* __restrict__ Wl,
                                               const float* __restrict__ bc,
                                               const float* __restrict__ bl,
                                               const float* __restrict__ dis,
                                               float* __restrict__ hconv2,
                                               float* __restrict__ base2) {
  __shared__ float h1s[32][64];      // 8 KB  [k][node]
  __shared__ float2 Wb[32][32];      // 8 KB  {Wc, Wl} interleaved
  const int t = threadIdx.x;
  const int n0 = blockIdx.x * 64;
  const int c = t & 31;
  const int g = t >> 5;              // node group 0..7
  float accC[8], accL[8];
  #pragma unroll
  for (int i = 0; i < 8; ++i) { accC[i] = 0.f; accL[i] = 0.f; }
  for (int kc = 0; kc < HID; kc += 32) {
    __syncthreads();
    // stage W chunk: 32 k x 32 cols (30 used)
    {
      int kk = t >> 5, cc = t & 31;
      #pragma unroll
      for (int r = 0; r < 4; ++r) {
        int k = kk + r * 8;
        float vc = 0.f, vl = 0.f;
        if (cc < KCL) {
          vc = Wc[(size_t)(kc + k) * KCL + cc];
          vl = Wl[(size_t)(kc + k) * KCL + cc];
        }
        Wb[k][cc] = make_float2(vc, vl);
      }
    }
    // stage h1 chunk transposed: [32 k][64 nodes], bf16 -> f32
    if (t < 128) {
      int nn = t >> 1, half = t & 1;
      int gn = n0 + nn;
      uint4 a = make_uint4(0, 0, 0, 0), b = make_uint4(0, 0, 0, 0);
      if (gn < N_NODES) {
        const uint4* p = (const uint4*)(h1b + (size_t)gn * HID + kc + half * 16);
        a = p[0]; b = p[1];
      }
      int kb = half * 16;
      const uint aw[4] = {a.x, a.y, a.z, a.w};
      const uint bw[4] = {b.x, b.y, b.z, b.w};
      #pragma unroll
      for (int q = 0; q < 4; ++q) {
        h1s[kb + q * 2 + 0][nn] = __uint_as_float(aw[q] << 16);
        h1s[kb + q * 2 + 1][nn] = __uint_as_float(aw[q] & 0xFFFF0000u);
        h1s[kb + 8 + q * 2 + 0][nn] = __uint_as_float(bw[q] << 16);
        h1s[kb + 8 + q * 2 + 1][nn] = __uint_as_float(bw[q] & 0xFFFF0000u);
      }
    }
    __syncthreads();
    #pragma unroll 8
    for (int kk = 0; kk < 32; ++kk) {
      float2 w2 = Wb[kk][c];
      const float4* hv = (const float4*)&h1s[kk][g * 8];
      float4 hA = hv[0], hB = hv[1];
      accC[0] = fmaf(hA.x, w2.x, accC[0]); accL[0] = fmaf(hA.x, w2.y, accL[0]);
      accC[1] = fmaf(hA.y, w2.x, accC[1]); accL[1] = fmaf(hA.y, w2.y, accL[1]);
      accC[2] = fmaf(hA.z, w2.x, accC[2]); accL[2] = fmaf(hA.z, w2.y, accL[2]);
      accC[3] = fmaf(hA.w, w2.x, accC[3]); accL[3] = fmaf(hA.w, w2.y, accL[3]);
      accC[4] = fmaf(hB.x, w2.x, accC[4]); accL[4] = fmaf(hB.x, w2.y, accL[4]);
      accC[5] = fmaf(hB.y, w2.x, accC[5]); accL[5] = fmaf(hB.y, w2.y, accL[5]);
      accC[6] = fmaf(hB.z, w2.x, accC[6]); accL[6] = fmaf(hB.z, w2.y, accL[6]);
      accC[7] = fmaf(hB.w, w2.x, accC[7]); accL[7] = fmaf(hB.w, w2.y, accL[7]);
    }
  }
  if (c < KCL) {
    float bcv = bc[c], blv = bl[c];
    #pragma unroll
    for (int i = 0; i < 8; ++i) {
      int gn = n0 + g * 8 + i;
      if (gn < N_NODES) {
        float d = dis[gn];
        hconv2[(size_t)gn * KCL + c] = accC[i];
        base2[(size_t)gn * KCL + c] = accL[i] + blv + bcv + d * d * accC[i];
      }
    }
  }
}

// ---------- layer-2 aggregation + softmax + clip + FX write + colsum/svec partials ----------
__global__ __launch_bounds__(256) void k_agg2(const int* __restrict__ rowptr,
                                              const int* __restrict__ csr_src,
                                              const float* __restrict__ csr_norm,
                                              const float* __restrict__ hconv2,
                                              const float* __restrict__ base2,
                                              const float* __restrict__ degree,
                                              float* __restrict__ FX,
                                              float* __restrict__ scal) {
  const int t = threadIdx.x;
  const int lane = t & 63, wid = t >> 6;
  const int half = lane >> 5, c = lane & 31;
  const int nwaves = gridDim.x * 4;
  const int gw = blockIdx.x * 4 + wid;
  float cs_acc = 0.f, s_acc = 0.f;
  for (int n = gw; n < N_NODES; n += nwaves) {
    int e0 = rowptr[n], e1 = rowptr[n + 1];
    float acc = 0.f;
    for (int j = e0 + half; j < e1; j += 2) {
      int src = csr_src[j];
      float nrm = csr_norm[j];
      if (c < KCL) acc = fmaf(nrm, hconv2[(size_t)src * KCL + c], acc);
    }
    acc += __shfl(acc, lane ^ 32);  // combine the two half-wave edge partitions
    float out = (c < KCL) ? acc + base2[(size_t)n * KCL + c] : -1e30f;
    float mx = out;
    #pragma unroll
    for (int o = 16; o > 0; o >>= 1) mx = fmaxf(mx, __shfl_xor(mx, o));
    float p = (c < KCL) ? __expf(out - mx) : 0.f;
    float sum = p;
    #pragma unroll
    for (int o = 16; o > 0; o >>= 1) sum += __shfl_xor(sum, o);
    float fx = p / sum;
    fx = fminf(fmaxf(fx, 1e-9f), 1.f - 1e-9f);
    if (half == 0 && c < KCL) FX[(size_t)n * KCL + c] = fx;
    float degv = degree[n];
    cs_acc += (c < KCL) ? fx : 0.f;
    s_acc += (c < KCL - 1) ? fx * degv : 0.f;
  }
  __shared__ float red_cs[4][32];
  __shared__ float red_s[4][32];
  if (half == 0) { red_cs[wid][c] = cs_acc; red_s[wid][c] = s_acc; }
  __syncthreads();
  if (t < 32) {
    float a = red_cs[0][t] + red_cs[1][t] + red_cs[2][t] + red_cs[3][t];
    float b = red_s[0][t] + red_s[1][t] + red_s[2][t] + red_s[3][t];
    if (t < KCL) atomicAdd(&scal[2 + t], a);
    if (t < KCL - 1) atomicAdd(&scal[32 + t], b);
  }
}

// ---------- modularity connectivity: sum_e w * dot(FX[r,:29], FX[c,:29]) ----------
__global__ __launch_bounds__(256) void k_conn(const int* __restrict__ ei,
                                              const float* __restrict__ w,
                                              const float* __restrict__ FX,
                                              float* __restrict__ conn) {
  int e = blockIdx.x * 256 + threadIdx.x;
  float val = 0.f;
  if (e < N_EDGES) {
    int r = ei[e], cc = ei[N_EDGES + e];
    const float2* fr = (const float2*)(FX + (size_t)r * KCL);
    const float2* fc = (const float2*)(FX + (size_t)cc * KCL);
    float dot = 0.f;
    #pragma unroll
    for (int k = 0; k < 14; ++k) {
      float2 a = fr[k], b = fc[k];
      dot += a.x * b.x + a.y * b.y;
    }
    dot += FX[(size_t)r * KCL + 28] * FX[(size_t)cc * KCL + 28];
    val = w[e] * dot;
  }
  #pragma unroll
  for (int o = 32; o > 0; o >>= 1) val += __shfl_down(val, o);
  __shared__ float ls[4];
  int lane = threadIdx.x & 63, wid = threadIdx.x >> 6;
  if (lane == 0) ls[wid] = val;
  __syncthreads();
  if (threadIdx.x == 0) atomicAdd(conn, ls[0] + ls[1] + ls[2] + ls[3]);
}

// ---------- final scalar loss ----------
__global__ void k_finalize(const float* __restrict__ scal, float* __restrict__ out_loss) {
  if (threadIdx.x == 0 && blockIdx.x == 0) {
    float m = scal[0], conn = scal[1];
    float ss = 0.f;
    for (int k = 0; k < KCL - 1; ++k) { float s = scal[32 + k]; ss += s * s; }
    float cs2 = 0.f;
    for (int k = 0; k < KCL; ++k) { float cv = scal[2 + k]; cs2 += cv * cv; }
    float avg = ss / (2.f * m);
    float modularity = -(conn - avg) / (2.f * m);
    float reg = sqrtf(cs2 + 1e-9f) * sqrtf((float)KCL) / (float)N_NODES - 1.f;
    out_loss[0] = modularity + 0.01f * reg;
  }
}

extern "C" void kernel_launch(void* const* d_in, const int* in_sizes, int n_in,
                              void* d_out, int out_size, void* d_ws, size_t ws_size,
                              hipStream_t stream) {
  const float* x   = (const float*)d_in[0];
  const int*   ei  = (const int*)d_in[1];
  const float* ea  = (const float*)d_in[2];
  const float* Wc1 = (const float*)d_in[3];
  const float* bc1 = (const float*)d_in[4];
  const float* Wl1 = (const float*)d_in[5];
  const float* bl1 = (const float*)d_in[6];
  const float* Wc2 = (const float*)d_in[7];
  const float* bc2 = (const float*)d_in[8];
  const float* Wl2 = (const float*)d_in[9];
  const float* bl2 = (const float*)d_in[10];
  float* out = (float*)d_out;

  float* ws = (float*)d_ws;
  size_t o = 0;
  float* deg_w  = ws + o; o += N_NODES;
  float* degree = ws + o; o += N_NODES;
  int*   cnt    = (int*)(ws + o); o += N_NODES;
  int*   fill   = (int*)(ws + o); o += N_NODES;
  float* scal   = ws + o; o += 64;
  size_t zero_floats = o;                       // everything above needs zeroing
  float* dis    = ws + o; o += N_NODES;
  int*   rowptr = (int*)(ws + o); o += N_NODES + 8;
  int*   csr_src= (int*)(ws + o); o += N_EDGES;
  float* csr_nrm= ws + o; o += N_EDGES;
  ushort* hconv_bf = (ushort*)(ws + o); o += (size_t)N_NODES * HID / 2;
  float* base1  = ws + o; o += (size_t)N_NODES * HID;
  ushort* h1b   = (ushort*)(ws + o); o += (size_t)N_NODES * HID / 2;
  float* hconv2 = ws + o; o += (size_t)N_NODES * KCL;
  float* base2  = ws + o; o += (size_t)N_NODES * KCL;
  o += 64;  // slack for speculative over-reads
  if (ws_size < o * sizeof(float)) return;  // insufficient workspace — bail safely

  hipMemsetAsync(d_ws, 0, zero_floats * sizeof(float), stream);

  k_pass1<<<N_EDGES / 256, 256, 0, stream>>>(ei, ea, deg_w, degree, cnt, scal);
  k_dis<<<(N_NODES + 255) / 256, 256, 0, stream>>>(deg_w, dis);
  k_scan<<<1, 1024, 0, stream>>>(cnt, rowptr);
  k_csrfill<<<N_EDGES / 256, 256, 0, stream>>>(ei, ea, dis, rowptr, fill, csr_src, csr_nrm);
  k_gemm1<<<N_NODES / NT1, 256, 0, stream>>>(x, Wc1, Wl1, bc1, bl1, dis, hconv_bf, base1);
  k_agg1<<<N_NODES, 256, 0, stream>>>(rowptr, csr_src, csr_nrm, hconv_bf, base1, h1b);
  k_gemm2<<<(N_NODES + 63) / 64, 256, 0, stream>>>(h1b, Wc2, Wl2, bc2, bl2, dis, hconv2, base2);
  k_agg2<<<1024, 256, 0, stream>>>(rowptr, csr_src, csr_nrm, hconv2, base2, degree, out, scal);
  k_conn<<<N_EDGES / 256, 256, 0, stream>>>(ei, ea, out, scal + 1);
  k_finalize<<<1, 64, 0, stream>>>(scal, out + (size_t)N_NODES * KCL);
}

// Round 3
// 1554.816 us; speedup vs baseline: 1.4131x; 1.1397x over previous
//
#include <hip/hip_runtime.h>
#include <hip/hip_bf16.h>
#include <math.h>

#define N_NODES 100000
#define N_EDGES 3200000
#define F_IN 128
#define HID 256
#define KCL 30
#define NT1 32
#define NCOPY 8

typedef unsigned int uint;
typedef unsigned short ushort;

static __device__ __forceinline__ float bf2f(ushort u) {
  return __uint_as_float(((uint)u) << 16);
}
static __device__ __forceinline__ ushort f2bf(float f) {
  uint u = __float_as_uint(f);
  uint r = (u + 0x7FFF + ((u >> 16) & 1)) >> 16;   // round-to-nearest-even
  return (ushort)r;
}

// scal layout: [0]=m, [1]=connectivity, [2..31]=colsum(30), [32..60]=svec(29)

// ---------- cnt8: XCD-privatized edge-count histogram (keyed by col) + m ----------
__global__ __launch_bounds__(256) void k_cnt8(const int* __restrict__ ei,
                                              const float* __restrict__ w,
                                              int* __restrict__ cnt8,
                                              float* __restrict__ m_out) {
  int e = blockIdx.x * 256 + threadIdx.x;
  int g = blockIdx.x & (NCOPY - 1);
  int c = ei[N_EDGES + e];
  float wv = w[e];
  atomicAdd(cnt8 + (size_t)g * N_NODES + c, 1);
  float s = wv;
  #pragma unroll
  for (int o = 32; o > 0; o >>= 1) s += __shfl_down(s, o);
  __shared__ float ls[4];
  int lane = threadIdx.x & 63, wid = threadIdx.x >> 6;
  if (lane == 0) ls[wid] = s;
  __syncthreads();
  if (threadIdx.x == 0) atomicAdd(m_out, ls[0] + ls[1] + ls[2] + ls[3]);
}

// ---------- scan8: exclusive scan of 800K counts (node-major, 8 copies/node) ----------
// off8[n*8+g] = start of node n's sub-segment for copy g; off8[N*8] = E.
__global__ __launch_bounds__(1024) void k_scan8(const int* __restrict__ cnt8,
                                                int* __restrict__ off8) {
  __shared__ int wsum[16];
  __shared__ int s_carry;
  const int t = threadIdx.x;
  const int lane = t & 63, wid = t >> 6;
  if (t == 0) s_carry = 0;
  __syncthreads();
  for (int nbase = 0; nbase < N_NODES; nbase += 1024) {
    int node = nbase + t;
    int v[NCOPY];
    int tot = 0;
    #pragma unroll
    for (int g = 0; g < NCOPY; ++g) {
      int x = (node < N_NODES) ? cnt8[(size_t)g * N_NODES + node] : 0;
      v[g] = tot;          // exclusive within-thread prefix
      tot += x;
    }
    int x = tot;
    #pragma unroll
    for (int o = 1; o < 64; o <<= 1) {
      int y = __shfl_up(x, o);
      if (lane >= o) x += y;
    }
    if (lane == 63) wsum[wid] = x;
    __syncthreads();
    if (t < 16) {
      int s = wsum[t];
      #pragma unroll
      for (int o = 1; o < 16; o <<= 1) {
        int y = __shfl_up(s, o);
        if (t >= o) s += y;
      }
      wsum[t] = s;
    }
    __syncthreads();
    int excl = s_carry + (wid ? wsum[wid - 1] : 0) + x - tot;
    if (node < N_NODES) {
      #pragma unroll
      for (int g = 0; g < NCOPY; ++g) off8[(size_t)node * NCOPY + g] = excl + v[g];
    }
    __syncthreads();
    if (t == 0) s_carry += wsum[15];
    __syncthreads();
  }
  if (t == 0) off8[(size_t)N_NODES * NCOPY] = N_EDGES;
}

// ---------- csrfill8: scatter (src, w) into XCD sub-segments via atomicSub on cnt8 ----------
__global__ __launch_bounds__(256) void k_csrfill8(const int* __restrict__ ei,
                                                  const float* __restrict__ w,
                                                  int* __restrict__ cnt8,
                                                  const int* __restrict__ off8,
                                                  int* __restrict__ csr_src,
                                                  float* __restrict__ csr_w) {
  int e = blockIdx.x * 256 + threadIdx.x;
  int g = blockIdx.x & (NCOPY - 1);
  int r = ei[e], c = ei[N_EDGES + e];
  int idx = atomicSub(cnt8 + (size_t)g * N_NODES + c, 1) - 1;
  int pos = off8[(size_t)c * NCOPY + g] + idx;
  csr_src[pos] = r;
  csr_w[pos] = w[e];
}

// ---------- degdis: dis[n] = rsqrt(row-sum of w + 1), sequential reads, no atomics ----------
__global__ __launch_bounds__(256) void k_degdis(const int* __restrict__ off8,
                                                const float* __restrict__ csr_w,
                                                float* __restrict__ dis) {
  int n = blockIdx.x * 256 + threadIdx.x;
  if (n >= N_NODES) return;
  int e0 = off8[(size_t)n * NCOPY];
  int e1 = off8[(size_t)(n + 1) * NCOPY];
  float s = 0.f;
  for (int j = e0; j < e1; ++j) s += csr_w[j];
  dis[n] = rsqrtf(s + 1.f);
}

// ---------- layer-1 dual GEMM: hconv(bf16) = x@Wc ; base1 = x@Wl + bl + bc + dis^2*hconv ----------
__global__ __launch_bounds__(256) void k_gemm1(const float* __restrict__ x,
                                               const float* __restrict__ Wc,
                                               const float* __restrict__ Wl,
                                               const float* __restrict__ bc,
                                               const float* __restrict__ bl,
                                               const float* __restrict__ dis,
                                               ushort* __restrict__ hconv_bf,
                                               float* __restrict__ base1) {
  __shared__ float xsT[F_IN][NT1];   // 16 KB  [k][node]
  __shared__ float WcS[32][HID];     // 32 KB
  __shared__ float WlS[32][HID];     // 32 KB
  const int t = threadIdx.x;
  const int n0 = blockIdx.x * NT1;
  {
    int n = t & 31, kb = t >> 5;   // kb in 0..7
    const float* xr = x + (size_t)(n0 + n) * F_IN + kb * 16;
    #pragma unroll
    for (int j = 0; j < 16; ++j) xsT[kb * 16 + j][n] = xr[j];
  }
  float accC[NT1], accL[NT1];
  #pragma unroll
  for (int i = 0; i < NT1; ++i) { accC[i] = 0.f; accL[i] = 0.f; }
  const int c = t;  // output column, 0..255
  for (int kc = 0; kc < F_IN; kc += 32) {
    __syncthreads();
    const float4* Wc4 = (const float4*)(Wc + (size_t)kc * HID);
    const float4* Wl4 = (const float4*)(Wl + (size_t)kc * HID);
    #pragma unroll
    for (int i = 0; i < 8; ++i) {
      int idx = t + i * 256;          // 2048 float4 per 32xHID chunk
      int kk = idx >> 6, c4 = idx & 63;
      *((float4*)&WcS[kk][c4 * 4]) = Wc4[(size_t)kk * 64 + c4];
      *((float4*)&WlS[kk][c4 * 4]) = Wl4[(size_t)kk * 64 + c4];
    }
    __syncthreads();
    for (int kk = 0; kk < 32; ++kk) {
      float wc = WcS[kk][c], wl = WlS[kk][c];
      const float4* xv = (const float4*)&xsT[kc + kk][0];
      #pragma unroll
      for (int q = 0; q < 8; ++q) {
        float4 v = xv[q];
        accC[q * 4 + 0] += v.x * wc; accL[q * 4 + 0] += v.x * wl;
        accC[q * 4 + 1] += v.y * wc; accL[q * 4 + 1] += v.y * wl;
        accC[q * 4 + 2] += v.z * wc; accL[q * 4 + 2] += v.z * wl;
        accC[q * 4 + 3] += v.w * wc; accL[q * 4 + 3] += v.w * wl;
      }
    }
  }
  float bcv = bc[c], blv = bl[c];
  #pragma unroll
  for (int n = 0; n < NT1; ++n) {
    int gn = n0 + n;
    float d = dis[gn];
    float hc = accC[n];
    hconv_bf[(size_t)gn * HID + c] = f2bf(hc);
    base1[(size_t)gn * HID + c] = accL[n] + blv + bcv + d * d * hc;
  }
}

// ---------- layer-1 aggregation: h1 = relu(dis_n * sum_e (dis_src*w)*hconv[src] + base1) ----------
__global__ __launch_bounds__(256) void k_agg1(const int* __restrict__ off8,
                                              const int* __restrict__ csr_src,
                                              const float* __restrict__ csr_w,
                                              const float* __restrict__ dis,
                                              const ushort* __restrict__ hconv_bf,
                                              const float* __restrict__ base1,
                                              ushort* __restrict__ h1b) {
  const int n = blockIdx.x;
  const int t = threadIdx.x;
  const int lane = t & 63, wid = t >> 6;
  const int e0 = off8[(size_t)n * NCOPY];
  const int e1 = off8[(size_t)(n + 1) * NCOPY];
  __shared__ int s_src[256];
  __shared__ float s_pn[256];
  __shared__ float red[4][256];
  float acc0 = 0.f, acc1 = 0.f, acc2 = 0.f, acc3 = 0.f;
  for (int jb = e0; jb < e1; jb += 256) {
    int cn = min(256, e1 - jb);
    __syncthreads();
    if (t < cn) {
      int s = csr_src[jb + t];
      s_src[t] = s;
      s_pn[t] = dis[s] * csr_w[jb + t];
    }
    __syncthreads();
    int j = wid;
    for (; j + 4 < cn; j += 8) {
      int sA = s_src[j];         float nA = s_pn[j];
      int sB = s_src[j + 4];     float nB = s_pn[j + 4];
      ushort4 vA = *(const ushort4*)(hconv_bf + (size_t)sA * HID + lane * 4);
      ushort4 vB = *(const ushort4*)(hconv_bf + (size_t)sB * HID + lane * 4);
      acc0 = fmaf(nA, bf2f(vA.x), acc0); acc1 = fmaf(nA, bf2f(vA.y), acc1);
      acc2 = fmaf(nA, bf2f(vA.z), acc2); acc3 = fmaf(nA, bf2f(vA.w), acc3);
      acc0 = fmaf(nB, bf2f(vB.x), acc0); acc1 = fmaf(nB, bf2f(vB.y), acc1);
      acc2 = fmaf(nB, bf2f(vB.z), acc2); acc3 = fmaf(nB, bf2f(vB.w), acc3);
    }
    if (j < cn) {
      int sA = s_src[j]; float nA = s_pn[j];
      ushort4 vA = *(const ushort4*)(hconv_bf + (size_t)sA * HID + lane * 4);
      acc0 = fmaf(nA, bf2f(vA.x), acc0); acc1 = fmaf(nA, bf2f(vA.y), acc1);
      acc2 = fmaf(nA, bf2f(vA.z), acc2); acc3 = fmaf(nA, bf2f(vA.w), acc3);
    }
  }
  __syncthreads();
  ((float4*)red[wid])[lane] = make_float4(acc0, acc1, acc2, acc3);
  __syncthreads();
  float dn = dis[n];
  float v = dn * (red[0][t] + red[1][t] + red[2][t] + red[3][t]) + base1[(size_t)n * HID + t];
  h1b[(size_t)n * HID + t] = f2bf(fmaxf(v, 0.f));
}

// ---------- layer-2 dual GEMM (register-blocked): hconv2(bf16) = h1@Wc2 ; base2 = h1@Wl2 + ... ----------
__global__ __launch_bounds__(256) void k_gemm2(const ushort* __restrict__ h1b,
                                               const float* __restrict__ Wc,
                                               const float* __restrict__ Wl,
                                               const float* __restrict__ bc,
                                               const float* __restrict__ bl,
                                               const float* __restrict__ dis,
                                               ushort* __restrict__ hconv2_bf,
                                               float* __restrict__ base2) {
  __shared__ float h1s[32][64];      // 8 KB  [k][node]
  __shared__ float2 Wb[32][32];      // 8 KB  {Wc, Wl} interleaved
  const int t = threadIdx.x;
  const int n0 = blockIdx.x * 64;
  const int c = t & 31;
  const int g = t >> 5;              // node group 0..7
  float accC[8], accL[8];
  #pragma unroll
  for (int i = 0; i < 8; ++i) { accC[i] = 0.f; accL[i] = 0.f; }
  for (int kc = 0; kc < HID; kc += 32) {
    __syncthreads();
    {
      int kk = t >> 5, cc = t & 31;
      #pragma unroll
      for (int r = 0; r < 4; ++r) {
        int k = kk + r * 8;
        float vc = 0.f, vl = 0.f;
        if (cc < KCL) {
          vc = Wc[(size_t)(kc + k) * KCL + cc];
          vl = Wl[(size_t)(kc + k) * KCL + cc];
        }
        Wb[k][cc] = make_float2(vc, vl);
      }
    }
    if (t < 128) {
      int nn = t >> 1, half = t & 1;
      int gn = n0 + nn;
      uint4 a = make_uint4(0, 0, 0, 0), b = make_uint4(0, 0, 0, 0);
      if (gn < N_NODES) {
        const uint4* p = (const uint4*)(h1b + (size_t)gn * HID + kc + half * 16);
        a = p[0]; b = p[1];
      }
      int kb = half * 16;
      const uint aw[4] = {a.x, a.y, a.z, a.w};
      const uint bw[4] = {b.x, b.y, b.z, b.w};
      #pragma unroll
      for (int q = 0; q < 4; ++q) {
        h1s[kb + q * 2 + 0][nn] = __uint_as_float(aw[q] << 16);
        h1s[kb + q * 2 + 1][nn] = __uint_as_float(aw[q] & 0xFFFF0000u);
        h1s[kb + 8 + q * 2 + 0][nn] = __uint_as_float(bw[q] << 16);
        h1s[kb + 8 + q * 2 + 1][nn] = __uint_as_float(bw[q] & 0xFFFF0000u);
      }
    }
    __syncthreads();
    #pragma unroll 8
    for (int kk = 0; kk < 32; ++kk) {
      float2 w2 = Wb[kk][c];
      const float4* hv = (const float4*)&h1s[kk][g * 8];
      float4 hA = hv[0], hB = hv[1];
      accC[0] = fmaf(hA.x, w2.x, accC[0]); accL[0] = fmaf(hA.x, w2.y, accL[0]);
      accC[1] = fmaf(hA.y, w2.x, accC[1]); accL[1] = fmaf(hA.y, w2.y, accL[1]);
      accC[2] = fmaf(hA.z, w2.x, accC[2]); accL[2] = fmaf(hA.z, w2.y, accL[2]);
      accC[3] = fmaf(hA.w, w2.x, accC[3]); accL[3] = fmaf(hA.w, w2.y, accL[3]);
      accC[4] = fmaf(hB.x, w2.x, accC[4]); accL[4] = fmaf(hB.x, w2.y, accL[4]);
      accC[5] = fmaf(hB.y, w2.x, accC[5]); accL[5] = fmaf(hB.y, w2.y, accL[5]);
      accC[6] = fmaf(hB.z, w2.x, accC[6]); accL[6] = fmaf(hB.z, w2.y, accL[6]);
      accC[7] = fmaf(hB.w, w2.x, accC[7]); accL[7] = fmaf(hB.w, w2.y, accL[7]);
    }
  }
  if (c < KCL) {
    float bcv = bc[c], blv = bl[c];
    #pragma unroll
    for (int i = 0; i < 8; ++i) {
      int gn = n0 + g * 8 + i;
      if (gn < N_NODES) {
        float d = dis[gn];
        hconv2_bf[(size_t)gn * KCL + c] = f2bf(accC[i]);
        base2[(size_t)gn * KCL + c] = accL[i] + blv + bcv + d * d * accC[i];
      }
    }
  }
}

// ---------- layer-2 aggregation + softmax + clip + FX write + colsum partials ----------
__global__ __launch_bounds__(256) void k_agg2(const int* __restrict__ off8,
                                              const int* __restrict__ csr_src,
                                              const float* __restrict__ csr_w,
                                              const float* __restrict__ dis,
                                              const ushort* __restrict__ hconv2_bf,
                                              const float* __restrict__ base2,
                                              float* __restrict__ FX,
                                              float* __restrict__ scal) {
  const int t = threadIdx.x;
  const int lane = t & 63, wid = t >> 6;
  const int half = lane >> 5, c = lane & 31;
  const int nwaves = gridDim.x * 4;
  const int gw = blockIdx.x * 4 + wid;
  float cs_acc = 0.f;
  for (int n = gw; n < N_NODES; n += nwaves) {
    int e0 = off8[(size_t)n * NCOPY];
    int e1 = off8[(size_t)(n + 1) * NCOPY];
    float acc = 0.f;
    for (int j = e0 + half; j < e1; j += 2) {
      int src = csr_src[j];
      float pn = dis[src] * csr_w[j];
      if (c < KCL) acc = fmaf(pn, bf2f(hconv2_bf[(size_t)src * KCL + c]), acc);
    }
    acc += __shfl(acc, lane ^ 32);  // combine the two half-wave edge partitions
    float out = (c < KCL) ? acc * dis[n] + base2[(size_t)n * KCL + c] : -1e30f;
    float mx = out;
    #pragma unroll
    for (int o = 16; o > 0; o >>= 1) mx = fmaxf(mx, __shfl_xor(mx, o));
    float p = (c < KCL) ? __expf(out - mx) : 0.f;
    float sum = p;
    #pragma unroll
    for (int o = 16; o > 0; o >>= 1) sum += __shfl_xor(sum, o);
    float fx = p / sum;
    fx = fminf(fmaxf(fx, 1e-9f), 1.f - 1e-9f);
    if (half == 0 && c < KCL) FX[(size_t)n * KCL + c] = fx;
    cs_acc += (c < KCL) ? fx : 0.f;
  }
  __shared__ float red_cs[4][32];
  if (half == 0) red_cs[wid][c] = cs_acc;
  __syncthreads();
  if (t < KCL) {
    float a = red_cs[0][t] + red_cs[1][t] + red_cs[2][t] + red_cs[3][t];
    atomicAdd(&scal[2 + t], a);
  }
}

// ---------- connectivity + degree-weighted colsum s: per edge, conn += w*dot(FX[r,:29],FX[c,:29]),
// ---------- s_k += w*FX[r,k] (k<29)  [= segment degree fold, replaces degree array] ----------
__global__ __launch_bounds__(256) void k_conn(const int* __restrict__ ei,
                                              const float* __restrict__ w,
                                              const float* __restrict__ FX,
                                              float* __restrict__ scal) {
  const int t = threadIdx.x;
  const int lane = t & 63, wid = t >> 6;
  const size_t e0 = ((size_t)blockIdx.x * 256 + t) * 4;
  float sv[29];
  #pragma unroll
  for (int k = 0; k < 29; ++k) sv[k] = 0.f;
  float conn = 0.f;
  int4 rr = *(const int4*)(ei + e0);
  int4 cc = *(const int4*)(ei + N_EDGES + e0);
  float4 ww = *(const float4*)(w + e0);
  const int rA[4] = {rr.x, rr.y, rr.z, rr.w};
  const int cA[4] = {cc.x, cc.y, cc.z, cc.w};
  const float wA[4] = {ww.x, ww.y, ww.z, ww.w};
  #pragma unroll
  for (int q = 0; q < 4; ++q) {
    int r = rA[q], cN = cA[q];
    float wv = wA[q];
    const float2* fr = (const float2*)(FX + (size_t)r * KCL);
    const float2* fc = (const float2*)(FX + (size_t)cN * KCL);
    float dot = 0.f;
    #pragma unroll
    for (int k = 0; k < 14; ++k) {
      float2 a = fr[k], b = fc[k];
      dot += a.x * b.x + a.y * b.y;
      sv[2 * k] = fmaf(wv, a.x, sv[2 * k]);
      sv[2 * k + 1] = fmaf(wv, a.y, sv[2 * k + 1]);
    }
    float a28 = FX[(size_t)r * KCL + 28], b28 = FX[(size_t)cN * KCL + 28];
    dot += a28 * b28;
    sv[28] = fmaf(wv, a28, sv[28]);
    conn = fmaf(wv, dot, conn);
  }
  __shared__ float red[4][30];
  #pragma unroll
  for (int i = 0; i < 30; ++i) {
    float v = (i < 29) ? sv[i] : conn;
    #pragma unroll
    for (int o = 32; o > 0; o >>= 1) v += __shfl_down(v, o);
    if (lane == 0) red[wid][i] = v;
  }
  __syncthreads();
  if (t < 30) {
    float s = red[0][t] + red[1][t] + red[2][t] + red[3][t];
    atomicAdd(t == 29 ? &scal[1] : &scal[32 + t], s);
  }
}

// ---------- final scalar loss ----------
__global__ void k_finalize(const float* __restrict__ scal, float* __restrict__ out_loss) {
  if (threadIdx.x == 0 && blockIdx.x == 0) {
    float m = scal[0], conn = scal[1];
    float ss = 0.f;
    for (int k = 0; k < KCL - 1; ++k) { float s = scal[32 + k]; ss += s * s; }
    float cs2 = 0.f;
    for (int k = 0; k < KCL; ++k) { float cv = scal[2 + k]; cs2 += cv * cv; }
    float avg = ss / (2.f * m);
    float modularity = -(conn - avg) / (2.f * m);
    float reg = sqrtf(cs2 + 1e-9f) * sqrtf((float)KCL) / (float)N_NODES - 1.f;
    out_loss[0] = modularity + 0.01f * reg;
  }
}

extern "C" void kernel_launch(void* const* d_in, const int* in_sizes, int n_in,
                              void* d_out, int out_size, void* d_ws, size_t ws_size,
                              hipStream_t stream) {
  const float* x   = (const float*)d_in[0];
  const int*   ei  = (const int*)d_in[1];
  const float* ea  = (const float*)d_in[2];
  const float* Wc1 = (const float*)d_in[3];
  const float* bc1 = (const float*)d_in[4];
  const float* Wl1 = (const float*)d_in[5];
  const float* bl1 = (const float*)d_in[6];
  const float* Wc2 = (const float*)d_in[7];
  const float* bc2 = (const float*)d_in[8];
  const float* Wl2 = (const float*)d_in[9];
  const float* bl2 = (const float*)d_in[10];
  float* out = (float*)d_out;

  float* ws = (float*)d_ws;
  size_t o = 0;
  int*   cnt8   = (int*)(ws + o); o += (size_t)NCOPY * N_NODES;  // zeroed
  float* scal   = ws + o; o += 64;                               // zeroed
  size_t zero_floats = o;
  int*   off8   = (int*)(ws + o); o += (size_t)N_NODES * NCOPY + 8;
  float* dis    = ws + o; o += N_NODES;
  int*   csr_src= (int*)(ws + o); o += N_EDGES;
  float* csr_w  = ws + o; o += N_EDGES;
  ushort* hconv_bf = (ushort*)(ws + o); o += (size_t)N_NODES * HID / 2;
  float* base1  = ws + o; o += (size_t)N_NODES * HID;
  ushort* h1b   = (ushort*)(ws + o); o += (size_t)N_NODES * HID / 2;
  ushort* hconv2_bf = (ushort*)(ws + o); o += (size_t)N_NODES * KCL / 2;
  float* base2  = ws + o; o += (size_t)N_NODES * KCL;
  o += 64;  // slack
  if (ws_size < o * sizeof(float)) return;  // insufficient workspace — bail safely

  hipMemsetAsync(d_ws, 0, zero_floats * sizeof(float), stream);

  k_cnt8<<<N_EDGES / 256, 256, 0, stream>>>(ei, ea, cnt8, scal);
  k_scan8<<<1, 1024, 0, stream>>>(cnt8, off8);
  k_csrfill8<<<N_EDGES / 256, 256, 0, stream>>>(ei, ea, cnt8, off8, csr_src, csr_w);
  k_degdis<<<(N_NODES + 255) / 256, 256, 0, stream>>>(off8, csr_w, dis);
  k_gemm1<<<N_NODES / NT1, 256, 0, stream>>>(x, Wc1, Wl1, bc1, bl1, dis, hconv_bf, base1);
  k_agg1<<<N_NODES, 256, 0, stream>>>(off8, csr_src, csr_w, dis, hconv_bf, base1, h1b);
  k_gemm2<<<(N_NODES + 63) / 64, 256, 0, stream>>>(h1b, Wc2, Wl2, bc2, bl2, dis, hconv2_bf, base2);
  k_agg2<<<1024, 256, 0, stream>>>(off8, csr_src, csr_w, dis, hconv2_bf, base2, out, scal);
  k_conn<<<N_EDGES / 1024, 256, 0, stream>>>(ei, ea, out, scal);
  k_finalize<<<1, 64, 0, stream>>>(scal, out + (size_t)N_NODES * KCL);
}

// Round 4
// 1303.684 us; speedup vs baseline: 1.6853x; 1.1926x over previous
//
#include <hip/hip_runtime.h>
#include <hip/hip_bf16.h>
#include <math.h>

#define N_NODES 100000
#define N_EDGES 3200000
#define F_IN 128
#define HID 256
#define KCL 30
#define NCOPY 8

typedef unsigned int uint;
typedef unsigned short ushort;
typedef __attribute__((ext_vector_type(8))) short bf16x8;
typedef __attribute__((ext_vector_type(4))) float f32x4;

static __device__ __forceinline__ float bf2f(ushort u) {
  return __uint_as_float(((uint)u) << 16);
}
static __device__ __forceinline__ float bf2f_hi(uint u) {
  return __uint_as_float(u & 0xFFFF0000u);
}
static __device__ __forceinline__ ushort f2bf(float f) {
  uint u = __float_as_uint(f);
  uint r = (u + 0x7FFF + ((u >> 16) & 1)) >> 16;   // round-to-nearest-even
  return (ushort)r;
}

// scal layout: [0]=m, [1]=connectivity, [2..31]=colsum(30), [32..60]=svec(29)

// ---------- cnt8: XCD-privatized edge-count histogram (keyed by col) ----------
__global__ __launch_bounds__(256) void k_cnt8(const int* __restrict__ ei,
                                              int* __restrict__ cnt8) {
  int e = blockIdx.x * 256 + threadIdx.x;
  int g = blockIdx.x & (NCOPY - 1);
  int c = ei[N_EDGES + e];
  atomicAdd(cnt8 + (size_t)g * N_NODES + c, 1);
}

// ---------- scan8: exclusive scan of 800K counts (node-major, 8 copies/node) ----------
__global__ __launch_bounds__(1024) void k_scan8(const int* __restrict__ cnt8,
                                                int* __restrict__ off8) {
  __shared__ int wsum[16];
  __shared__ int s_carry;
  const int t = threadIdx.x;
  const int lane = t & 63, wid = t >> 6;
  if (t == 0) s_carry = 0;
  __syncthreads();
  for (int nbase = 0; nbase < N_NODES; nbase += 1024) {
    int node = nbase + t;
    int v[NCOPY];
    int tot = 0;
    #pragma unroll
    for (int g = 0; g < NCOPY; ++g) {
      int x = (node < N_NODES) ? cnt8[(size_t)g * N_NODES + node] : 0;
      v[g] = tot;
      tot += x;
    }
    int x = tot;
    #pragma unroll
    for (int o = 1; o < 64; o <<= 1) {
      int y = __shfl_up(x, o);
      if (lane >= o) x += y;
    }
    if (lane == 63) wsum[wid] = x;
    __syncthreads();
    if (t < 16) {
      int s = wsum[t];
      #pragma unroll
      for (int o = 1; o < 16; o <<= 1) {
        int y = __shfl_up(s, o);
        if (t >= o) s += y;
      }
      wsum[t] = s;
    }
    __syncthreads();
    int excl = s_carry + (wid ? wsum[wid - 1] : 0) + x - tot;
    if (node < N_NODES) {
      #pragma unroll
      for (int g = 0; g < NCOPY; ++g) off8[(size_t)node * NCOPY + g] = excl + v[g];
    }
    __syncthreads();
    if (t == 0) s_carry += wsum[15];
    __syncthreads();
  }
  if (t == 0) off8[(size_t)N_NODES * NCOPY] = N_EDGES;
}

// ---------- csrfill8: scatter (src, w) into XCD sub-segments via atomicSub on cnt8 ----------
__global__ __launch_bounds__(256) void k_csrfill8(const int* __restrict__ ei,
                                                  const float* __restrict__ w,
                                                  int* __restrict__ cnt8,
                                                  const int* __restrict__ off8,
                                                  int* __restrict__ csr_src,
                                                  float* __restrict__ csr_w) {
  int e = blockIdx.x * 256 + threadIdx.x;
  int g = blockIdx.x & (NCOPY - 1);
  int r = ei[e], c = ei[N_EDGES + e];
  int idx = atomicSub(cnt8 + (size_t)g * N_NODES + c, 1) - 1;
  int pos = off8[(size_t)c * NCOPY + g] + idx;
  csr_src[pos] = r;
  csr_w[pos] = w[e];
}

// ---------- degdis: dis[n] = rsqrt(row-sum of w + 1); block-reduce partial m ----------
__global__ __launch_bounds__(256) void k_degdis(const int* __restrict__ off8,
                                                const float* __restrict__ csr_w,
                                                float* __restrict__ dis,
                                                float* __restrict__ m_out) {
  int n = blockIdx.x * 256 + threadIdx.x;
  float s = 0.f;
  if (n < N_NODES) {
    int e0 = off8[(size_t)n * NCOPY];
    int e1 = off8[(size_t)(n + 1) * NCOPY];
    for (int j = e0; j < e1; ++j) s += csr_w[j];
    dis[n] = rsqrtf(s + 1.f);
  }
  float v = s;
  #pragma unroll
  for (int o = 32; o > 0; o >>= 1) v += __shfl_down(v, o);
  __shared__ float ls[4];
  int lane = threadIdx.x & 63, wid = threadIdx.x >> 6;
  if (lane == 0) ls[wid] = v;
  __syncthreads();
  if (threadIdx.x == 0) atomicAdd(m_out, ls[0] + ls[1] + ls[2] + ls[3]);
}

// ---------- wprep: WT1[vc][k] = bf16(W[k][c]), vc<256 -> Wc1, vc>=256 -> Wl1 ----------
__global__ __launch_bounds__(256) void k_wprep(const float* __restrict__ Wc,
                                               const float* __restrict__ Wl,
                                               ushort* __restrict__ WT1) {
  int idx = blockIdx.x * 256 + threadIdx.x;   // 16384 total
  int vc = idx >> 5;
  int kq = (idx & 31) * 4;
  const float* W = (vc < HID) ? Wc : Wl;
  int c = vc & (HID - 1);
  ushort4 u;
  u.x = f2bf(W[(size_t)(kq + 0) * HID + c]);
  u.y = f2bf(W[(size_t)(kq + 1) * HID + c]);
  u.z = f2bf(W[(size_t)(kq + 2) * HID + c]);
  u.w = f2bf(W[(size_t)(kq + 3) * HID + c]);
  *(ushort4*)(WT1 + (size_t)vc * F_IN + kq) = u;
}

// ---------- layer-1 dual GEMM via MFMA bf16 ----------
// Block: 32 rows (BM=32, 100000 = 3125*32 exact), colhalf cb covers Wc cols cb*128..+127
// and matching Wl cols. 4 waves: wave w owns 32 Wc cols + 32 matching Wl cols.
// A-frag (16x32): lane l -> row l%16, k = (l>>4)*8 + j. B-frag: lane l -> col l%16, same k.
// C/D: col = lane&15, row = (lane>>4)*4 + reg  [verified m89].
__global__ __launch_bounds__(256) void k_gemm1m(const float* __restrict__ x,
                                                const ushort* __restrict__ WT1,
                                                const float* __restrict__ bc,
                                                const float* __restrict__ bl,
                                                const float* __restrict__ dis,
                                                ushort* __restrict__ hconv_bf,
                                                float* __restrict__ base1) {
  __shared__ ushort xs[32 * F_IN];   // 8 KB, XOR-swizzled bf16
  const int t = threadIdx.x;
  const int lane = t & 63, wid = t >> 6;
  const int mt = blockIdx.x >> 1, cb = blockIdx.x & 1;
  const int m0 = mt * 32;
  // stage x tile 32x128 fp32 -> bf16 swizzled
  {
    int row = t >> 3, k0 = (t & 7) * 16;
    const float4* xp = (const float4*)(x + (size_t)(m0 + row) * F_IN + k0);
    #pragma unroll
    for (int q = 0; q < 4; ++q) {
      float4 v = xp[q];
      ushort4 u = make_ushort4(f2bf(v.x), f2bf(v.y), f2bf(v.z), f2bf(v.w));
      int k = k0 + q * 4;
      *(ushort4*)&xs[row * F_IN + (k ^ ((row & 7) << 3))] = u;
    }
  }
  // B frags from WT1 (L2-resident). f = cs*2+cf: {C0,C1,L0,L1}
  bf16x8 B[4][4];
  const int vbase = cb * 128 + wid * 32 + (lane & 15);
  const int kb = (lane >> 4) * 8;
  #pragma unroll
  for (int cs = 0; cs < 2; ++cs)
    #pragma unroll
    for (int cf = 0; cf < 2; ++cf)
      #pragma unroll
      for (int ks = 0; ks < 4; ++ks) {
        int vc = cs * HID + vbase + cf * 16;
        B[cs * 2 + cf][ks] = *(const bf16x8*)(WT1 + (size_t)vc * F_IN + ks * 32 + kb);
      }
  f32x4 acc[2][4];
  #pragma unroll
  for (int fm = 0; fm < 2; ++fm)
    #pragma unroll
    for (int f = 0; f < 4; ++f) acc[fm][f] = (f32x4){0.f, 0.f, 0.f, 0.f};
  __syncthreads();
  const int r0 = lane & 15, r1 = 16 + (lane & 15);
  #pragma unroll
  for (int ks = 0; ks < 4; ++ks) {
    int k = ks * 32 + kb;
    bf16x8 A0 = *(const bf16x8*)&xs[r0 * F_IN + (k ^ ((r0 & 7) << 3))];
    bf16x8 A1 = *(const bf16x8*)&xs[r1 * F_IN + (k ^ ((r1 & 7) << 3))];
    #pragma unroll
    for (int f = 0; f < 4; ++f) {
      acc[0][f] = __builtin_amdgcn_mfma_f32_16x16x32_bf16(A0, B[f][ks], acc[0][f], 0, 0, 0);
      acc[1][f] = __builtin_amdgcn_mfma_f32_16x16x32_bf16(A1, B[f][ks], acc[1][f], 0, 0, 0);
    }
  }
  // epilogue: hconv (bf16) + base1 = lin + bl + bc + dis^2*hconv, pairing in-lane
  const int rb = (lane >> 4) * 4;
  #pragma unroll
  for (int cf = 0; cf < 2; ++cf) {
    int c = cb * 128 + wid * 32 + cf * 16 + (lane & 15);
    float bcv = bc[c], blv = bl[c];
    #pragma unroll
    for (int fm = 0; fm < 2; ++fm) {
      #pragma unroll
      for (int r = 0; r < 4; ++r) {
        int row = m0 + fm * 16 + rb + r;
        float hc = acc[fm][cf][r];
        float hl = acc[fm][2 + cf][r];
        float d = dis[row];
        hconv_bf[(size_t)row * HID + c] = f2bf(hc);
        base1[(size_t)row * HID + c] = hl + blv + bcv + d * d * hc;
      }
    }
  }
}

// ---------- layer-1 aggregation: h1 = relu(dis_n * sum_e (dis_src*w)*hconv[src] + base1) ----------
__global__ __launch_bounds__(256) void k_agg1(const int* __restrict__ off8,
                                              const int* __restrict__ csr_src,
                                              const float* __restrict__ csr_w,
                                              const float* __restrict__ dis,
                                              const ushort* __restrict__ hconv_bf,
                                              const float* __restrict__ base1,
                                              ushort* __restrict__ h1b) {
  const int n = blockIdx.x;
  const int t = threadIdx.x;
  const int lane = t & 63, wid = t >> 6;
  const int e0 = off8[(size_t)n * NCOPY];
  const int e1 = off8[(size_t)(n + 1) * NCOPY];
  __shared__ int s_src[256];
  __shared__ float s_pn[256];
  __shared__ float red[4][256];
  float acc0 = 0.f, acc1 = 0.f, acc2 = 0.f, acc3 = 0.f;
  for (int jb = e0; jb < e1; jb += 256) {
    int cn = min(256, e1 - jb);
    __syncthreads();
    if (t < cn) {
      int s = csr_src[jb + t];
      s_src[t] = s;
      s_pn[t] = dis[s] * csr_w[jb + t];
    }
    __syncthreads();
    int j = wid;
    for (; j + 4 < cn; j += 8) {
      int sA = s_src[j];         float nA = s_pn[j];
      int sB = s_src[j + 4];     float nB = s_pn[j + 4];
      ushort4 vA = *(const ushort4*)(hconv_bf + (size_t)sA * HID + lane * 4);
      ushort4 vB = *(const ushort4*)(hconv_bf + (size_t)sB * HID + lane * 4);
      acc0 = fmaf(nA, bf2f(vA.x), acc0); acc1 = fmaf(nA, bf2f(vA.y), acc1);
      acc2 = fmaf(nA, bf2f(vA.z), acc2); acc3 = fmaf(nA, bf2f(vA.w), acc3);
      acc0 = fmaf(nB, bf2f(vB.x), acc0); acc1 = fmaf(nB, bf2f(vB.y), acc1);
      acc2 = fmaf(nB, bf2f(vB.z), acc2); acc3 = fmaf(nB, bf2f(vB.w), acc3);
    }
    if (j < cn) {
      int sA = s_src[j]; float nA = s_pn[j];
      ushort4 vA = *(const ushort4*)(hconv_bf + (size_t)sA * HID + lane * 4);
      acc0 = fmaf(nA, bf2f(vA.x), acc0); acc1 = fmaf(nA, bf2f(vA.y), acc1);
      acc2 = fmaf(nA, bf2f(vA.z), acc2); acc3 = fmaf(nA, bf2f(vA.w), acc3);
    }
  }
  __syncthreads();
  ((float4*)red[wid])[lane] = make_float4(acc0, acc1, acc2, acc3);
  __syncthreads();
  float dn = dis[n];
  float v = dn * (red[0][t] + red[1][t] + red[2][t] + red[3][t]) + base1[(size_t)n * HID + t];
  h1b[(size_t)n * HID + t] = f2bf(fmaxf(v, 0.f));
}

// ---------- layer-2 dual GEMM (register-blocked): hconv2(bf16) = h1@Wc2 ; base2 = h1@Wl2 + ... ----------
__global__ __launch_bounds__(256) void k_gemm2(const ushort* __restrict__ h1b,
                                               const float* __restrict__ Wc,
                                               const float* __restrict__ Wl,
                                               const float* __restrict__ bc,
                                               const float* __restrict__ bl,
                                               const float* __restrict__ dis,
                                               ushort* __restrict__ hconv2_bf,
                                               float* __restrict__ base2) {
  __shared__ float h1s[32][64];      // 8 KB  [k][node]
  __shared__ float2 Wb[32][32];      // 8 KB  {Wc, Wl} interleaved
  const int t = threadIdx.x;
  const int n0 = blockIdx.x * 64;
  const int c = t & 31;
  const int g = t >> 5;              // node group 0..7
  float accC[8], accL[8];
  #pragma unroll
  for (int i = 0; i < 8; ++i) { accC[i] = 0.f; accL[i] = 0.f; }
  for (int kc = 0; kc < HID; kc += 32) {
    __syncthreads();
    {
      int kk = t >> 5, cc = t & 31;
      #pragma unroll
      for (int r = 0; r < 4; ++r) {
        int k = kk + r * 8;
        float vc = 0.f, vl = 0.f;
        if (cc < KCL) {
          vc = Wc[(size_t)(kc + k) * KCL + cc];
          vl = Wl[(size_t)(kc + k) * KCL + cc];
        }
        Wb[k][cc] = make_float2(vc, vl);
      }
    }
    if (t < 128) {
      int nn = t >> 1, half = t & 1;
      int gn = n0 + nn;
      uint4 a = make_uint4(0, 0, 0, 0), b = make_uint4(0, 0, 0, 0);
      if (gn < N_NODES) {
        const uint4* p = (const uint4*)(h1b + (size_t)gn * HID + kc + half * 16);
        a = p[0]; b = p[1];
      }
      int kb = half * 16;
      const uint aw[4] = {a.x, a.y, a.z, a.w};
      const uint bw[4] = {b.x, b.y, b.z, b.w};
      #pragma unroll
      for (int q = 0; q < 4; ++q) {
        h1s[kb + q * 2 + 0][nn] = __uint_as_float(aw[q] << 16);
        h1s[kb + q * 2 + 1][nn] = __uint_as_float(aw[q] & 0xFFFF0000u);
        h1s[kb + 8 + q * 2 + 0][nn] = __uint_as_float(bw[q] << 16);
        h1s[kb + 8 + q * 2 + 1][nn] = __uint_as_float(bw[q] & 0xFFFF0000u);
      }
    }
    __syncthreads();
    #pragma unroll 8
    for (int kk = 0; kk < 32; ++kk) {
      float2 w2 = Wb[kk][c];
      const float4* hv = (const float4*)&h1s[kk][g * 8];
      float4 hA = hv[0], hB = hv[1];
      accC[0] = fmaf(hA.x, w2.x, accC[0]); accL[0] = fmaf(hA.x, w2.y, accL[0]);
      accC[1] = fmaf(hA.y, w2.x, accC[1]); accL[1] = fmaf(hA.y, w2.y, accL[1]);
      accC[2] = fmaf(hA.z, w2.x, accC[2]); accL[2] = fmaf(hA.z, w2.y, accL[2]);
      accC[3] = fmaf(hA.w, w2.x, accC[3]); accL[3] = fmaf(hA.w, w2.y, accL[3]);
      accC[4] = fmaf(hB.x, w2.x, accC[4]); accL[4] = fmaf(hB.x, w2.y, accL[4]);
      accC[5] = fmaf(hB.y, w2.x, accC[5]); accL[5] = fmaf(hB.y, w2.y, accL[5]);
      accC[6] = fmaf(hB.z, w2.x, accC[6]); accL[6] = fmaf(hB.z, w2.y, accL[6]);
      accC[7] = fmaf(hB.w, w2.x, accC[7]); accL[7] = fmaf(hB.w, w2.y, accL[7]);
    }
  }
  if (c < KCL) {
    float bcv = bc[c], blv = bl[c];
    #pragma unroll
    for (int i = 0; i < 8; ++i) {
      int gn = n0 + g * 8 + i;
      if (gn < N_NODES) {
        float d = dis[gn];
        hconv2_bf[(size_t)gn * KCL + c] = f2bf(accC[i]);
        base2[(size_t)gn * KCL + c] = accL[i] + blv + bcv + d * d * accC[i];
      }
    }
  }
}

// ---------- layer-2 aggregation + softmax + clip + FX(fp32) + FXb(bf16) + colsum ----------
__global__ __launch_bounds__(256) void k_agg2(const int* __restrict__ off8,
                                              const int* __restrict__ csr_src,
                                              const float* __restrict__ csr_w,
                                              const float* __restrict__ dis,
                                              const ushort* __restrict__ hconv2_bf,
                                              const float* __restrict__ base2,
                                              float* __restrict__ FX,
                                              ushort* __restrict__ FXb,
                                              float* __restrict__ scal) {
  const int t = threadIdx.x;
  const int lane = t & 63, wid = t >> 6;
  const int half = lane >> 5, c = lane & 31;
  const int nwaves = gridDim.x * 4;
  const int gw = blockIdx.x * 4 + wid;
  float cs_acc = 0.f;
  for (int n = gw; n < N_NODES; n += nwaves) {
    int e0 = off8[(size_t)n * NCOPY];
    int e1 = off8[(size_t)(n + 1) * NCOPY];
    float acc = 0.f;
    for (int j = e0 + half; j < e1; j += 2) {
      int src = csr_src[j];
      float pn = dis[src] * csr_w[j];
      if (c < KCL) acc = fmaf(pn, bf2f(hconv2_bf[(size_t)src * KCL + c]), acc);
    }
    acc += __shfl(acc, lane ^ 32);
    float out = (c < KCL) ? acc * dis[n] + base2[(size_t)n * KCL + c] : -1e30f;
    float mx = out;
    #pragma unroll
    for (int o = 16; o > 0; o >>= 1) mx = fmaxf(mx, __shfl_xor(mx, o));
    float p = (c < KCL) ? __expf(out - mx) : 0.f;
    float sum = p;
    #pragma unroll
    for (int o = 16; o > 0; o >>= 1) sum += __shfl_xor(sum, o);
    float fx = p / sum;
    fx = fminf(fmaxf(fx, 1e-9f), 1.f - 1e-9f);
    if (half == 0 && c < KCL) {
      FX[(size_t)n * KCL + c] = fx;
      FXb[(size_t)n * KCL + c] = f2bf(fx);
    }
    cs_acc += (c < KCL) ? fx : 0.f;
  }
  __shared__ float red_cs[4][32];
  if (half == 0) red_cs[wid][c] = cs_acc;
  __syncthreads();
  if (t < KCL) {
    float a = red_cs[0][t] + red_cs[1][t] + red_cs[2][t] + red_cs[3][t];
    atomicAdd(&scal[2 + t], a);
  }
}

// ---------- connectivity + degree-weighted colsum s over bf16 FX shadow ----------
__global__ __launch_bounds__(256) void k_conn(const int* __restrict__ ei,
                                              const float* __restrict__ w,
                                              const ushort* __restrict__ FXb,
                                              float* __restrict__ scal) {
  const int t = threadIdx.x;
  const int lane = t & 63, wid = t >> 6;
  const size_t e0 = ((size_t)blockIdx.x * 256 + t) * 4;
  float sv[29];
  #pragma unroll
  for (int k = 0; k < 29; ++k) sv[k] = 0.f;
  float conn = 0.f;
  int4 rr = *(const int4*)(ei + e0);
  int4 cc = *(const int4*)(ei + N_EDGES + e0);
  float4 ww = *(const float4*)(w + e0);
  const int rA[4] = {rr.x, rr.y, rr.z, rr.w};
  const int cA[4] = {cc.x, cc.y, cc.z, cc.w};
  const float wA[4] = {ww.x, ww.y, ww.z, ww.w};
  #pragma unroll
  for (int q = 0; q < 4; ++q) {
    int r = rA[q], cN = cA[q];
    float wv = wA[q];
    const uint* fr = (const uint*)(FXb + (size_t)r * KCL);   // 15 uints (60B, 4B-aligned)
    const uint* fc = (const uint*)(FXb + (size_t)cN * KCL);
    float dot = 0.f;
    #pragma unroll
    for (int k = 0; k < 14; ++k) {
      uint ua = fr[k], ub = fc[k];
      float a0 = bf2f((ushort)(ua & 0xFFFF)), a1 = bf2f_hi(ua);
      float b0 = bf2f((ushort)(ub & 0xFFFF)), b1 = bf2f_hi(ub);
      dot += a0 * b0 + a1 * b1;
      sv[2 * k] = fmaf(wv, a0, sv[2 * k]);
      sv[2 * k + 1] = fmaf(wv, a1, sv[2 * k + 1]);
    }
    float a28 = bf2f((ushort)(fr[14] & 0xFFFF));
    float b28 = bf2f((ushort)(fc[14] & 0xFFFF));
    dot += a28 * b28;
    sv[28] = fmaf(wv, a28, sv[28]);
    conn = fmaf(wv, dot, conn);
  }
  __shared__ float red[4][30];
  #pragma unroll
  for (int i = 0; i < 30; ++i) {
    float v = (i < 29) ? sv[i] : conn;
    #pragma unroll
    for (int o = 32; o > 0; o >>= 1) v += __shfl_down(v, o);
    if (lane == 0) red[wid][i] = v;
  }
  __syncthreads();
  if (t < 30) {
    float s = red[0][t] + red[1][t] + red[2][t] + red[3][t];
    atomicAdd(t == 29 ? &scal[1] : &scal[32 + t], s);
  }
}

// ---------- final scalar loss ----------
__global__ void k_finalize(const float* __restrict__ scal, float* __restrict__ out_loss) {
  if (threadIdx.x == 0 && blockIdx.x == 0) {
    float m = scal[0], conn = scal[1];
    float ss = 0.f;
    for (int k = 0; k < KCL - 1; ++k) { float s = scal[32 + k]; ss += s * s; }
    float cs2 = 0.f;
    for (int k = 0; k < KCL; ++k) { float cv = scal[2 + k]; cs2 += cv * cv; }
    float avg = ss / (2.f * m);
    float modularity = -(conn - avg) / (2.f * m);
    float reg = sqrtf(cs2 + 1e-9f) * sqrtf((float)KCL) / (float)N_NODES - 1.f;
    out_loss[0] = modularity + 0.01f * reg;
  }
}

extern "C" void kernel_launch(void* const* d_in, const int* in_sizes, int n_in,
                              void* d_out, int out_size, void* d_ws, size_t ws_size,
                              hipStream_t stream) {
  const float* x   = (const float*)d_in[0];
  const int*   ei  = (const int*)d_in[1];
  const float* ea  = (const float*)d_in[2];
  const float* Wc1 = (const float*)d_in[3];
  const float* bc1 = (const float*)d_in[4];
  const float* Wl1 = (const float*)d_in[5];
  const float* bl1 = (const float*)d_in[6];
  const float* Wc2 = (const float*)d_in[7];
  const float* bc2 = (const float*)d_in[8];
  const float* Wl2 = (const float*)d_in[9];
  const float* bl2 = (const float*)d_in[10];
  float* out = (float*)d_out;

  float* ws = (float*)d_ws;
  size_t o = 0;
  int*   cnt8   = (int*)(ws + o); o += (size_t)NCOPY * N_NODES;  // zeroed
  float* scal   = ws + o; o += 64;                               // zeroed
  size_t zero_floats = o;
  int*   off8   = (int*)(ws + o); o += (size_t)N_NODES * NCOPY + 8;
  float* dis    = ws + o; o += N_NODES;
  int*   csr_src= (int*)(ws + o); o += N_EDGES;
  float* csr_w  = ws + o; o += N_EDGES;
  ushort* WT1   = (ushort*)(ws + o); o += (size_t)512 * F_IN / 2;
  ushort* hconv_bf = (ushort*)(ws + o); o += (size_t)N_NODES * HID / 2;
  float* base1  = ws + o; o += (size_t)N_NODES * HID;
  ushort* h1b   = (ushort*)(ws + o); o += (size_t)N_NODES * HID / 2;
  ushort* hconv2_bf = (ushort*)(ws + o); o += (size_t)N_NODES * KCL / 2;
  float* base2  = ws + o; o += (size_t)N_NODES * KCL;
  o += 64;  // slack
  if (ws_size < o * sizeof(float)) return;  // insufficient workspace — bail safely

  // FXb aliases hconv_bf (dead after k_agg1; FXb written by k_agg2, read by k_conn)
  ushort* FXb = hconv_bf;

  hipMemsetAsync(d_ws, 0, zero_floats * sizeof(float), stream);

  k_cnt8<<<N_EDGES / 256, 256, 0, stream>>>(ei, cnt8);
  k_scan8<<<1, 1024, 0, stream>>>(cnt8, off8);
  k_csrfill8<<<N_EDGES / 256, 256, 0, stream>>>(ei, ea, cnt8, off8, csr_src, csr_w);
  k_degdis<<<(N_NODES + 255) / 256, 256, 0, stream>>>(off8, csr_w, dis, scal);
  k_wprep<<<64, 256, 0, stream>>>(Wc1, Wl1, WT1);
  k_gemm1m<<<(N_NODES / 32) * 2, 256, 0, stream>>>(x, WT1, bc1, bl1, dis, hconv_bf, base1);
  k_agg1<<<N_NODES, 256, 0, stream>>>(off8, csr_src, csr_w, dis, hconv_bf, base1, h1b);
  k_gemm2<<<(N_NODES + 63) / 64, 256, 0, stream>>>(h1b, Wc2, Wl2, bc2, bl2, dis, hconv2_bf, base2);
  k_agg2<<<1024, 256, 0, stream>>>(off8, csr_src, csr_w, dis, hconv2_bf, base2, out, FXb, scal);
  k_conn<<<N_EDGES / 1024, 256, 0, stream>>>(ei, ea, FXb, scal);
  k_finalize<<<1, 64, 0, stream>>>(scal, out + (size_t)N_NODES * KCL);
}

// Round 5
// 1248.935 us; speedup vs baseline: 1.7592x; 1.0438x over previous
//
#include <hip/hip_runtime.h>
#include <hip/hip_bf16.h>
#include <math.h>

#define N_NODES 100000
#define N_EDGES 3200000
#define F_IN 128
#define HID 256
#define KCL 30
#define NCOPY 8

typedef unsigned int uint;
typedef unsigned short ushort;
typedef __attribute__((ext_vector_type(8))) short bf16x8;
typedef __attribute__((ext_vector_type(4))) float f32x4;

static __device__ __forceinline__ float bf2f(ushort u) {
  return __uint_as_float(((uint)u) << 16);
}
static __device__ __forceinline__ float bf2f_hi(uint u) {
  return __uint_as_float(u & 0xFFFF0000u);
}
static __device__ __forceinline__ ushort f2bf(float f) {
  uint u = __float_as_uint(f);
  uint r = (u + 0x7FFF + ((u >> 16) & 1)) >> 16;   // round-to-nearest-even
  return (ushort)r;
}

// scal layout: [0]=m, [1]=connectivity, [2..31]=colsum(30), [32..60]=svec(29)

// ---------- cnt8: XCD-privatized edge-count histogram (keyed by col) ----------
__global__ __launch_bounds__(256) void k_cnt8(const int* __restrict__ ei,
                                              int* __restrict__ cnt8) {
  int e = blockIdx.x * 256 + threadIdx.x;
  int g = blockIdx.x & (NCOPY - 1);
  int c = ei[N_EDGES + e];
  atomicAdd(cnt8 + (size_t)g * N_NODES + c, 1);
}

// ---------- scanA: per-1024-node block scan of 8-copy counts -> in-block off8 + block totals ----------
__global__ __launch_bounds__(1024) void k_scanA(const int* __restrict__ cnt8,
                                                int* __restrict__ off8,
                                                int* __restrict__ blocktot) {
  __shared__ int wsum[16];
  const int t = threadIdx.x;
  const int lane = t & 63, wid = t >> 6;
  int node = blockIdx.x * 1024 + t;
  int v[NCOPY];
  int tot = 0;
  if (node < N_NODES) {
    #pragma unroll
    for (int g = 0; g < NCOPY; ++g) {
      int x = cnt8[(size_t)g * N_NODES + node];
      v[g] = tot;
      tot += x;
    }
  } else {
    #pragma unroll
    for (int g = 0; g < NCOPY; ++g) v[g] = 0;
  }
  int x = tot;
  #pragma unroll
  for (int o = 1; o < 64; o <<= 1) {
    int y = __shfl_up(x, o);
    if (lane >= o) x += y;
  }
  if (lane == 63) wsum[wid] = x;
  __syncthreads();
  if (t < 16) {
    int s = wsum[t];
    #pragma unroll
    for (int o = 1; o < 16; o <<= 1) {
      int y = __shfl_up(s, o);
      if (t >= o) s += y;
    }
    wsum[t] = s;
  }
  __syncthreads();
  int excl = (wid ? wsum[wid - 1] : 0) + x - tot;
  if (node < N_NODES) {
    #pragma unroll
    for (int g = 0; g < NCOPY; ++g) off8[(size_t)node * NCOPY + g] = excl + v[g];
  }
  if (t == 0) blocktot[blockIdx.x] = wsum[15];
}

// ---------- scanB: serial exclusive scan of 98 block totals (trivial) ----------
__global__ void k_scanB(const int* __restrict__ blocktot, int* __restrict__ blockoff) {
  if (threadIdx.x == 0 && blockIdx.x == 0) {
    int acc = 0;
    for (int b = 0; b < 98; ++b) { blockoff[b] = acc; acc += blocktot[b]; }
  }
}

// ---------- scanC: add block offsets; set sentinel ----------
__global__ __launch_bounds__(256) void k_scanC(int* __restrict__ off8,
                                               const int* __restrict__ blockoff) {
  int idx = blockIdx.x * 256 + threadIdx.x;
  if (idx > N_NODES * NCOPY) return;
  if (idx == N_NODES * NCOPY) { off8[idx] = N_EDGES; return; }
  off8[idx] += blockoff[idx >> 13];   // node = idx>>3, block = node>>10
}

// ---------- csrfill8: scatter (src, w) into XCD sub-segments via atomicSub on cnt8 ----------
__global__ __launch_bounds__(256) void k_csrfill8(const int* __restrict__ ei,
                                                  const float* __restrict__ w,
                                                  int* __restrict__ cnt8,
                                                  const int* __restrict__ off8,
                                                  int* __restrict__ csr_src,
                                                  float* __restrict__ csr_w) {
  int e = blockIdx.x * 256 + threadIdx.x;
  int g = blockIdx.x & (NCOPY - 1);
  int r = ei[e], c = ei[N_EDGES + e];
  int idx = atomicSub(cnt8 + (size_t)g * N_NODES + c, 1) - 1;
  int pos = off8[(size_t)c * NCOPY + g] + idx;
  csr_src[pos] = r;
  csr_w[pos] = w[e];
}

// ---------- degdis: dis[n] = rsqrt(row-sum of w + 1); block-reduce partial m ----------
__global__ __launch_bounds__(256) void k_degdis(const int* __restrict__ off8,
                                                const float* __restrict__ csr_w,
                                                float* __restrict__ dis,
                                                float* __restrict__ m_out) {
  int n = blockIdx.x * 256 + threadIdx.x;
  float s = 0.f;
  if (n < N_NODES) {
    int e0 = off8[(size_t)n * NCOPY];
    int e1 = off8[(size_t)(n + 1) * NCOPY];
    for (int j = e0; j < e1; ++j) s += csr_w[j];
    dis[n] = rsqrtf(s + 1.f);
  }
  float v = s;
  #pragma unroll
  for (int o = 32; o > 0; o >>= 1) v += __shfl_down(v, o);
  __shared__ float ls[4];
  int lane = threadIdx.x & 63, wid = threadIdx.x >> 6;
  if (lane == 0) ls[wid] = v;
  __syncthreads();
  if (threadIdx.x == 0) atomicAdd(m_out, ls[0] + ls[1] + ls[2] + ls[3]);
}

// ---------- wprep: WT1[vc][k] = bf16(W[k][c]), vc<256 -> Wc1, vc>=256 -> Wl1 ----------
__global__ __launch_bounds__(256) void k_wprep(const float* __restrict__ Wc,
                                               const float* __restrict__ Wl,
                                               ushort* __restrict__ WT1) {
  int idx = blockIdx.x * 256 + threadIdx.x;   // 16384 total
  int vc = idx >> 5;
  int kq = (idx & 31) * 4;
  const float* W = (vc < HID) ? Wc : Wl;
  int c = vc & (HID - 1);
  ushort4 u;
  u.x = f2bf(W[(size_t)(kq + 0) * HID + c]);
  u.y = f2bf(W[(size_t)(kq + 1) * HID + c]);
  u.z = f2bf(W[(size_t)(kq + 2) * HID + c]);
  u.w = f2bf(W[(size_t)(kq + 3) * HID + c]);
  *(ushort4*)(WT1 + (size_t)vc * F_IN + kq) = u;
}

// ---------- wprep2: WT2[vc][k] = bf16(W2[k][c]), vc<32 -> Wc2 col vc, vc>=32 -> Wl2 col vc-32 ----------
__global__ __launch_bounds__(256) void k_wprep2(const float* __restrict__ Wc,
                                                const float* __restrict__ Wl,
                                                ushort* __restrict__ WT2) {
  int idx = blockIdx.x * 256 + threadIdx.x;   // 4096 total
  int vc = idx >> 6;
  int kq = (idx & 63) * 4;
  const float* W = (vc < 32) ? Wc : Wl;
  int c = vc & 31;
  ushort4 u = make_ushort4(0, 0, 0, 0);
  if (c < KCL) {
    u.x = f2bf(W[(size_t)(kq + 0) * KCL + c]);
    u.y = f2bf(W[(size_t)(kq + 1) * KCL + c]);
    u.z = f2bf(W[(size_t)(kq + 2) * KCL + c]);
    u.w = f2bf(W[(size_t)(kq + 3) * KCL + c]);
  }
  *(ushort4*)(WT2 + (size_t)vc * HID + kq) = u;
}

// ---------- layer-1 dual GEMM via MFMA bf16 (both col-halves per block; x staged once) ----------
__global__ __launch_bounds__(256) void k_gemm1m(const float* __restrict__ x,
                                                const ushort* __restrict__ WT1,
                                                const float* __restrict__ bc,
                                                const float* __restrict__ bl,
                                                const float* __restrict__ dis,
                                                ushort* __restrict__ hconv_bf,
                                                float* __restrict__ base1) {
  __shared__ ushort xs[32 * F_IN];   // 8 KB, XOR-swizzled bf16
  const int t = threadIdx.x;
  const int lane = t & 63, wid = t >> 6;
  const int m0 = blockIdx.x * 32;
  {
    int row = t >> 3, k0 = (t & 7) * 16;
    const float4* xp = (const float4*)(x + (size_t)(m0 + row) * F_IN + k0);
    #pragma unroll
    for (int q = 0; q < 4; ++q) {
      float4 v = xp[q];
      ushort4 u = make_ushort4(f2bf(v.x), f2bf(v.y), f2bf(v.z), f2bf(v.w));
      int k = k0 + q * 4;
      *(ushort4*)&xs[row * F_IN + (k ^ ((row & 7) << 3))] = u;
    }
  }
  __syncthreads();
  // A frags hoisted (shared across both col-halves)
  const int r0 = lane & 15, r1 = 16 + (lane & 15);
  const int kb = (lane >> 4) * 8;
  bf16x8 A0[4], A1[4];
  #pragma unroll
  for (int ks = 0; ks < 4; ++ks) {
    int k = ks * 32 + kb;
    A0[ks] = *(const bf16x8*)&xs[r0 * F_IN + (k ^ ((r0 & 7) << 3))];
    A1[ks] = *(const bf16x8*)&xs[r1 * F_IN + (k ^ ((r1 & 7) << 3))];
  }
  const int rb = (lane >> 4) * 4;
  #pragma unroll
  for (int cb = 0; cb < 2; ++cb) {
    bf16x8 B[4][4];   // f = cs*2+cf: {C0,C1,L0,L1}
    const int vbase = cb * 128 + wid * 32 + (lane & 15);
    #pragma unroll
    for (int cs = 0; cs < 2; ++cs)
      #pragma unroll
      for (int cf = 0; cf < 2; ++cf)
        #pragma unroll
        for (int ks = 0; ks < 4; ++ks) {
          int vc = cs * HID + vbase + cf * 16;
          B[cs * 2 + cf][ks] = *(const bf16x8*)(WT1 + (size_t)vc * F_IN + ks * 32 + kb);
        }
    f32x4 acc[2][4];
    #pragma unroll
    for (int fm = 0; fm < 2; ++fm)
      #pragma unroll
      for (int f = 0; f < 4; ++f) acc[fm][f] = (f32x4){0.f, 0.f, 0.f, 0.f};
    #pragma unroll
    for (int ks = 0; ks < 4; ++ks) {
      #pragma unroll
      for (int f = 0; f < 4; ++f) {
        acc[0][f] = __builtin_amdgcn_mfma_f32_16x16x32_bf16(A0[ks], B[f][ks], acc[0][f], 0, 0, 0);
        acc[1][f] = __builtin_amdgcn_mfma_f32_16x16x32_bf16(A1[ks], B[f][ks], acc[1][f], 0, 0, 0);
      }
    }
    #pragma unroll
    for (int cf = 0; cf < 2; ++cf) {
      int c = cb * 128 + wid * 32 + cf * 16 + (lane & 15);
      float bcv = bc[c], blv = bl[c];
      #pragma unroll
      for (int fm = 0; fm < 2; ++fm) {
        #pragma unroll
        for (int r = 0; r < 4; ++r) {
          int row = m0 + fm * 16 + rb + r;
          float hc = acc[fm][cf][r];
          float hl = acc[fm][2 + cf][r];
          float d = dis[row];
          hconv_bf[(size_t)row * HID + c] = f2bf(hc);
          base1[(size_t)row * HID + c] = hl + blv + bcv + d * d * hc;
        }
      }
    }
  }
}

// ---------- layer-1 aggregation: h1 = relu(dis_n * sum_e (dis_src*w)*hconv[src] + base1) ----------
__global__ __launch_bounds__(256) void k_agg1(const int* __restrict__ off8,
                                              const int* __restrict__ csr_src,
                                              const float* __restrict__ csr_w,
                                              const float* __restrict__ dis,
                                              const ushort* __restrict__ hconv_bf,
                                              const float* __restrict__ base1,
                                              ushort* __restrict__ h1b) {
  const int n = blockIdx.x;
  const int t = threadIdx.x;
  const int lane = t & 63, wid = t >> 6;
  const int e0 = off8[(size_t)n * NCOPY];
  const int e1 = off8[(size_t)(n + 1) * NCOPY];
  __shared__ int s_src[256];
  __shared__ float s_pn[256];
  __shared__ float red[4][256];
  float acc0 = 0.f, acc1 = 0.f, acc2 = 0.f, acc3 = 0.f;
  for (int jb = e0; jb < e1; jb += 256) {
    int cn = min(256, e1 - jb);
    __syncthreads();
    if (t < cn) {
      int s = csr_src[jb + t];
      s_src[t] = s;
      s_pn[t] = dis[s] * csr_w[jb + t];
    }
    __syncthreads();
    int j = wid;
    for (; j + 4 < cn; j += 8) {
      int sA = s_src[j];         float nA = s_pn[j];
      int sB = s_src[j + 4];     float nB = s_pn[j + 4];
      ushort4 vA = *(const ushort4*)(hconv_bf + (size_t)sA * HID + lane * 4);
      ushort4 vB = *(const ushort4*)(hconv_bf + (size_t)sB * HID + lane * 4);
      acc0 = fmaf(nA, bf2f(vA.x), acc0); acc1 = fmaf(nA, bf2f(vA.y), acc1);
      acc2 = fmaf(nA, bf2f(vA.z), acc2); acc3 = fmaf(nA, bf2f(vA.w), acc3);
      acc0 = fmaf(nB, bf2f(vB.x), acc0); acc1 = fmaf(nB, bf2f(vB.y), acc1);
      acc2 = fmaf(nB, bf2f(vB.z), acc2); acc3 = fmaf(nB, bf2f(vB.w), acc3);
    }
    if (j < cn) {
      int sA = s_src[j]; float nA = s_pn[j];
      ushort4 vA = *(const ushort4*)(hconv_bf + (size_t)sA * HID + lane * 4);
      acc0 = fmaf(nA, bf2f(vA.x), acc0); acc1 = fmaf(nA, bf2f(vA.y), acc1);
      acc2 = fmaf(nA, bf2f(vA.z), acc2); acc3 = fmaf(nA, bf2f(vA.w), acc3);
    }
  }
  __syncthreads();
  ((float4*)red[wid])[lane] = make_float4(acc0, acc1, acc2, acc3);
  __syncthreads();
  float dn = dis[n];
  float v = dn * (red[0][t] + red[1][t] + red[2][t] + red[3][t]) + base1[(size_t)n * HID + t];
  h1b[(size_t)n * HID + t] = f2bf(fmaxf(v, 0.f));
}

// ---------- layer-2 dual GEMM via MFMA bf16: 64 rows/block, wave owns 16 rows x 4 col-tiles ----------
// Padded outputs: hconv2p/base2p stride 32 (cols 0..29 valid).
__global__ __launch_bounds__(256) void k_gemm2m(const ushort* __restrict__ h1b,
                                                const ushort* __restrict__ WT2,
                                                const float* __restrict__ bc,
                                                const float* __restrict__ bl,
                                                const float* __restrict__ dis,
                                                ushort* __restrict__ hconv2p,
                                                float* __restrict__ base2p) {
  __shared__ ushort hs[64 * HID];    // 32 KB, XOR-swizzled bf16
  const int t = threadIdx.x;
  const int lane = t & 63, wid = t >> 6;
  const int n0 = blockIdx.x * 64;
  // stage h1 tile 64x256 bf16 (threads 0..3 cover row 0, etc. -> coalesced)
  {
    int row = t >> 2, kq = (t & 3) * 64;
    int gn = n0 + row;
    #pragma unroll
    for (int q = 0; q < 8; ++q) {
      int k = kq + q * 8;
      uint4 u = make_uint4(0, 0, 0, 0);
      if (gn < N_NODES) u = *(const uint4*)(h1b + (size_t)gn * HID + k);
      *(uint4*)&hs[row * HID + (k ^ ((row & 7) << 3))] = u;
    }
  }
  __syncthreads();
  const int lr = wid * 16 + (lane & 15);
  const int kb = (lane >> 4) * 8;
  f32x4 acc[4];
  #pragma unroll
  for (int f = 0; f < 4; ++f) acc[f] = (f32x4){0.f, 0.f, 0.f, 0.f};
  #pragma unroll
  for (int ks = 0; ks < 8; ++ks) {
    int k = ks * 32 + kb;
    bf16x8 A = *(const bf16x8*)&hs[lr * HID + (k ^ ((lr & 7) << 3))];
    #pragma unroll
    for (int f = 0; f < 4; ++f) {
      int vc = f * 16 + (lane & 15);
      bf16x8 B = *(const bf16x8*)(WT2 + (size_t)vc * HID + k);
      acc[f] = __builtin_amdgcn_mfma_f32_16x16x32_bf16(A, B, acc[f], 0, 0, 0);
    }
  }
  // epilogue: f 0,1 = Wc2 cols (lane&15)+16f ; f 2,3 = Wl2 same cols. Pair in-lane.
  const int rb = (lane >> 4) * 4;
  #pragma unroll
  for (int cf = 0; cf < 2; ++cf) {
    int c = cf * 16 + (lane & 15);
    if (c < KCL) {
      float bcv = bc[c], blv = bl[c];
      #pragma unroll
      for (int r = 0; r < 4; ++r) {
        int row = n0 + wid * 16 + rb + r;
        if (row < N_NODES) {
          float hc = acc[cf][r];
          float hl = acc[2 + cf][r];
          float d = dis[row];
          hconv2p[(size_t)row * 32 + c] = f2bf(hc);
          base2p[(size_t)row * 32 + c] = hl + blv + bcv + d * d * hc;
        }
      }
    }
  }
}

// ---------- layer-2 aggregation + softmax + clip + FX(fp32) + FXbp(bf16, stride 32) + colsum ----------
__global__ __launch_bounds__(256) void k_agg2(const int* __restrict__ off8,
                                              const int* __restrict__ csr_src,
                                              const float* __restrict__ csr_w,
                                              const float* __restrict__ dis,
                                              const ushort* __restrict__ hconv2p,
                                              const float* __restrict__ base2p,
                                              float* __restrict__ FX,
                                              ushort* __restrict__ FXbp,
                                              float* __restrict__ scal) {
  const int t = threadIdx.x;
  const int lane = t & 63, wid = t >> 6;
  const int half = lane >> 5, c = lane & 31;
  const int nwaves = gridDim.x * 4;
  const int gw = blockIdx.x * 4 + wid;
  float cs_acc = 0.f;
  for (int n = gw; n < N_NODES; n += nwaves) {
    int e0 = off8[(size_t)n * NCOPY];
    int e1 = off8[(size_t)(n + 1) * NCOPY];
    float acc = 0.f;
    for (int j = e0 + half; j < e1; j += 2) {
      int src = csr_src[j];
      float pn = dis[src] * csr_w[j];
      if (c < KCL) acc = fmaf(pn, bf2f(hconv2p[(size_t)src * 32 + c]), acc);
    }
    acc += __shfl(acc, lane ^ 32);
    float out = (c < KCL) ? acc * dis[n] + base2p[(size_t)n * 32 + c] : -1e30f;
    float mx = out;
    #pragma unroll
    for (int o = 16; o > 0; o >>= 1) mx = fmaxf(mx, __shfl_xor(mx, o));
    float p = (c < KCL) ? __expf(out - mx) : 0.f;
    float sum = p;
    #pragma unroll
    for (int o = 16; o > 0; o >>= 1) sum += __shfl_xor(sum, o);
    float fx = p / sum;
    fx = fminf(fmaxf(fx, 1e-9f), 1.f - 1e-9f);
    if (half == 0 && c < KCL) {
      FX[(size_t)n * KCL + c] = fx;
      FXbp[(size_t)n * 32 + c] = f2bf(fx);
    }
    cs_acc += (c < KCL) ? fx : 0.f;
  }
  __shared__ float red_cs[4][32];
  if (half == 0) red_cs[wid][c] = cs_acc;
  __syncthreads();
  if (t < KCL) {
    float a = red_cs[0][t] + red_cs[1][t] + red_cs[2][t] + red_cs[3][t];
    atomicAdd(&scal[2 + t], a);
  }
}

// ---------- connectivity + degree-weighted colsum s over bf16 FX shadow (stride 32) ----------
__global__ __launch_bounds__(256) void k_conn(const int* __restrict__ ei,
                                              const float* __restrict__ w,
                                              const ushort* __restrict__ FXbp,
                                              float* __restrict__ scal) {
  const int t = threadIdx.x;
  const int lane = t & 63, wid = t >> 6;
  const size_t e0 = ((size_t)blockIdx.x * 256 + t) * 4;
  float sv[29];
  #pragma unroll
  for (int k = 0; k < 29; ++k) sv[k] = 0.f;
  float conn = 0.f;
  int4 rr = *(const int4*)(ei + e0);
  int4 cc = *(const int4*)(ei + N_EDGES + e0);
  float4 ww = *(const float4*)(w + e0);
  const int rA[4] = {rr.x, rr.y, rr.z, rr.w};
  const int cA[4] = {cc.x, cc.y, cc.z, cc.w};
  const float wA[4] = {ww.x, ww.y, ww.z, ww.w};
  #pragma unroll
  for (int q = 0; q < 4; ++q) {
    int r = rA[q], cN = cA[q];
    float wv = wA[q];
    const uint* fr = (const uint*)FXbp + (size_t)r * 16;
    const uint* fc = (const uint*)FXbp + (size_t)cN * 16;
    float dot = 0.f;
    #pragma unroll
    for (int k = 0; k < 14; ++k) {
      uint ua = fr[k], ub = fc[k];
      float a0 = bf2f((ushort)(ua & 0xFFFF)), a1 = bf2f_hi(ua);
      float b0 = bf2f((ushort)(ub & 0xFFFF)), b1 = bf2f_hi(ub);
      dot += a0 * b0 + a1 * b1;
      sv[2 * k] = fmaf(wv, a0, sv[2 * k]);
      sv[2 * k + 1] = fmaf(wv, a1, sv[2 * k + 1]);
    }
    float a28 = bf2f((ushort)(fr[14] & 0xFFFF));
    float b28 = bf2f((ushort)(fc[14] & 0xFFFF));
    dot += a28 * b28;
    sv[28] = fmaf(wv, a28, sv[28]);
    conn = fmaf(wv, dot, conn);
  }
  __shared__ float red[4][30];
  #pragma unroll
  for (int i = 0; i < 30; ++i) {
    float v = (i < 29) ? sv[i] : conn;
    #pragma unroll
    for (int o = 32; o > 0; o >>= 1) v += __shfl_down(v, o);
    if (lane == 0) red[wid][i] = v;
  }
  __syncthreads();
  if (t < 30) {
    float s = red[0][t] + red[1][t] + red[2][t] + red[3][t];
    atomicAdd(t == 29 ? &scal[1] : &scal[32 + t], s);
  }
}

// ---------- final scalar loss ----------
__global__ void k_finalize(const float* __restrict__ scal, float* __restrict__ out_loss) {
  if (threadIdx.x == 0 && blockIdx.x == 0) {
    float m = scal[0], conn = scal[1];
    float ss = 0.f;
    for (int k = 0; k < KCL - 1; ++k) { float s = scal[32 + k]; ss += s * s; }
    float cs2 = 0.f;
    for (int k = 0; k < KCL; ++k) { float cv = scal[2 + k]; cs2 += cv * cv; }
    float avg = ss / (2.f * m);
    float modularity = -(conn - avg) / (2.f * m);
    float reg = sqrtf(cs2 + 1e-9f) * sqrtf((float)KCL) / (float)N_NODES - 1.f;
    out_loss[0] = modularity + 0.01f * reg;
  }
}

extern "C" void kernel_launch(void* const* d_in, const int* in_sizes, int n_in,
                              void* d_out, int out_size, void* d_ws, size_t ws_size,
                              hipStream_t stream) {
  const float* x   = (const float*)d_in[0];
  const int*   ei  = (const int*)d_in[1];
  const float* ea  = (const float*)d_in[2];
  const float* Wc1 = (const float*)d_in[3];
  const float* bc1 = (const float*)d_in[4];
  const float* Wl1 = (const float*)d_in[5];
  const float* bl1 = (const float*)d_in[6];
  const float* Wc2 = (const float*)d_in[7];
  const float* bc2 = (const float*)d_in[8];
  const float* Wl2 = (const float*)d_in[9];
  const float* bl2 = (const float*)d_in[10];
  float* out = (float*)d_out;

  float* ws = (float*)d_ws;
  size_t o = 0;
  int*   cnt8   = (int*)(ws + o); o += (size_t)NCOPY * N_NODES;  // zeroed
  float* scal   = ws + o; o += 64;                               // zeroed
  size_t zero_floats = o;
  int*   off8   = (int*)(ws + o); o += (size_t)N_NODES * NCOPY + 8;
  int*   blocktot = (int*)(ws + o); o += 128;
  int*   blockoff = (int*)(ws + o); o += 128;
  float* dis    = ws + o; o += N_NODES;
  int*   csr_src= (int*)(ws + o); o += N_EDGES;
  float* csr_w  = ws + o; o += N_EDGES;
  ushort* WT1   = (ushort*)(ws + o); o += (size_t)512 * F_IN / 2;
  ushort* WT2   = (ushort*)(ws + o); o += (size_t)64 * HID / 2;
  ushort* hconv_bf = (ushort*)(ws + o); o += (size_t)N_NODES * HID / 2;
  float* base1  = ws + o; o += (size_t)N_NODES * HID;
  ushort* h1b   = (ushort*)(ws + o); o += (size_t)N_NODES * HID / 2;
  ushort* hconv2p = (ushort*)(ws + o); o += (size_t)N_NODES * 32 / 2;
  float* base2p = ws + o; o += (size_t)N_NODES * 32;
  o += 64;  // slack
  if (ws_size < o * sizeof(float)) return;  // insufficient workspace — bail safely

  // FXbp aliases hconv_bf (dead after k_agg1); stride 32 ushorts
  ushort* FXbp = hconv_bf;

  hipMemsetAsync(d_ws, 0, zero_floats * sizeof(float), stream);

  k_cnt8<<<N_EDGES / 256, 256, 0, stream>>>(ei, cnt8);
  k_scanA<<<98, 1024, 0, stream>>>(cnt8, off8, blocktot);
  k_scanB<<<1, 64, 0, stream>>>(blocktot, blockoff);
  k_scanC<<<(N_NODES * NCOPY + 256) / 256, 256, 0, stream>>>(off8, blockoff);
  k_csrfill8<<<N_EDGES / 256, 256, 0, stream>>>(ei, ea, cnt8, off8, csr_src, csr_w);
  k_degdis<<<(N_NODES + 255) / 256, 256, 0, stream>>>(off8, csr_w, dis, scal);
  k_wprep<<<64, 256, 0, stream>>>(Wc1, Wl1, WT1);
  k_wprep2<<<16, 256, 0, stream>>>(Wc2, Wl2, WT2);
  k_gemm1m<<<N_NODES / 32, 256, 0, stream>>>(x, WT1, bc1, bl1, dis, hconv_bf, base1);
  k_agg1<<<N_NODES, 256, 0, stream>>>(off8, csr_src, csr_w, dis, hconv_bf, base1, h1b);
  k_gemm2m<<<(N_NODES + 63) / 64, 256, 0, stream>>>(h1b, WT2, bc2, bl2, dis, hconv2p, base2p);
  k_agg2<<<1024, 256, 0, stream>>>(off8, csr_src, csr_w, dis, hconv2p, base2p, out, FXbp, scal);
  k_conn<<<N_EDGES / 1024, 256, 0, stream>>>(ei, ea, FXbp, scal);
  k_finalize<<<1, 64, 0, stream>>>(scal, out + (size_t)N_NODES * KCL);
}

// Round 6
// 1007.444 us; speedup vs baseline: 2.1809x; 1.2397x over previous
//
#include <hip/hip_runtime.h>
#include <hip/hip_bf16.h>
#include <math.h>

#define N_NODES 100000
#define N_EDGES 3200000
#define F_IN 128
#define HID 256
#define KCL 30
#define NCOPY 8

typedef unsigned int uint;
typedef unsigned short ushort;
typedef __attribute__((ext_vector_type(8))) short bf16x8;
typedef __attribute__((ext_vector_type(4))) float f32x4;

static __device__ __forceinline__ float bf2f(ushort u) {
  return __uint_as_float(((uint)u) << 16);
}
static __device__ __forceinline__ float bf2f_hi(uint u) {
  return __uint_as_float(u & 0xFFFF0000u);
}
static __device__ __forceinline__ ushort f2bf(float f) {
  uint u = __float_as_uint(f);
  uint r = (u + 0x7FFF + ((u >> 16) & 1)) >> 16;   // round-to-nearest-even
  return (ushort)r;
}

// scal layout: [0]=m, [1]=connectivity, [2..31]=colsum(30), [32..60]=svec(29)

// ---------- cnt8: XCD-privatized edge-count histogram (keyed by col) ----------
__global__ __launch_bounds__(256) void k_cnt8(const int* __restrict__ ei,
                                              int* __restrict__ cnt8) {
  int e = blockIdx.x * 256 + threadIdx.x;
  int g = blockIdx.x & (NCOPY - 1);
  int c = ei[N_EDGES + e];
  atomicAdd(cnt8 + (size_t)g * N_NODES + c, 1);
}

// ---------- scanA: per-1024-node block scan of 8-copy counts -> in-block off8 + block totals ----------
__global__ __launch_bounds__(1024) void k_scanA(const int* __restrict__ cnt8,
                                                int* __restrict__ off8,
                                                int* __restrict__ blocktot) {
  __shared__ int wsum[16];
  const int t = threadIdx.x;
  const int lane = t & 63, wid = t >> 6;
  int node = blockIdx.x * 1024 + t;
  int v[NCOPY];
  int tot = 0;
  if (node < N_NODES) {
    #pragma unroll
    for (int g = 0; g < NCOPY; ++g) {
      int x = cnt8[(size_t)g * N_NODES + node];
      v[g] = tot;
      tot += x;
    }
  } else {
    #pragma unroll
    for (int g = 0; g < NCOPY; ++g) v[g] = 0;
  }
  int x = tot;
  #pragma unroll
  for (int o = 1; o < 64; o <<= 1) {
    int y = __shfl_up(x, o);
    if (lane >= o) x += y;
  }
  if (lane == 63) wsum[wid] = x;
  __syncthreads();
  if (t < 16) {
    int s = wsum[t];
    #pragma unroll
    for (int o = 1; o < 16; o <<= 1) {
      int y = __shfl_up(s, o);
      if (t >= o) s += y;
    }
    wsum[t] = s;
  }
  __syncthreads();
  int excl = (wid ? wsum[wid - 1] : 0) + x - tot;
  if (node < N_NODES) {
    #pragma unroll
    for (int g = 0; g < NCOPY; ++g) off8[(size_t)node * NCOPY + g] = excl + v[g];
  }
  if (t == 0) blocktot[blockIdx.x] = wsum[15];
}

// ---------- scanB: serial exclusive scan of 98 block totals (trivial) ----------
__global__ void k_scanB(const int* __restrict__ blocktot, int* __restrict__ blockoff) {
  if (threadIdx.x == 0 && blockIdx.x == 0) {
    int acc = 0;
    for (int b = 0; b < 98; ++b) { blockoff[b] = acc; acc += blocktot[b]; }
  }
}

// ---------- scanC: add block offsets; set sentinel ----------
__global__ __launch_bounds__(256) void k_scanC(int* __restrict__ off8,
                                               const int* __restrict__ blockoff) {
  int idx = blockIdx.x * 256 + threadIdx.x;
  if (idx > N_NODES * NCOPY) return;
  if (idx == N_NODES * NCOPY) { off8[idx] = N_EDGES; return; }
  off8[idx] += blockoff[idx >> 13];   // node = idx>>3, block = node>>10
}

// ---------- csrfill8: scatter (src, w) into XCD sub-segments via atomicSub on cnt8 ----------
__global__ __launch_bounds__(256) void k_csrfill8(const int* __restrict__ ei,
                                                  const float* __restrict__ w,
                                                  int* __restrict__ cnt8,
                                                  const int* __restrict__ off8,
                                                  int* __restrict__ csr_src,
                                                  float* __restrict__ csr_w) {
  int e = blockIdx.x * 256 + threadIdx.x;
  int g = blockIdx.x & (NCOPY - 1);
  int r = ei[e], c = ei[N_EDGES + e];
  int idx = atomicSub(cnt8 + (size_t)g * N_NODES + c, 1) - 1;
  int pos = off8[(size_t)c * NCOPY + g] + idx;
  csr_src[pos] = r;
  csr_w[pos] = w[e];
}

// ---------- degdis: dis[n] = rsqrt(row-sum of w + 1); block-reduce partial m ----------
__global__ __launch_bounds__(256) void k_degdis(const int* __restrict__ off8,
                                                const float* __restrict__ csr_w,
                                                float* __restrict__ dis,
                                                float* __restrict__ m_out) {
  int n = blockIdx.x * 256 + threadIdx.x;
  float s = 0.f;
  if (n < N_NODES) {
    int e0 = off8[(size_t)n * NCOPY];
    int e1 = off8[(size_t)(n + 1) * NCOPY];
    for (int j = e0; j < e1; ++j) s += csr_w[j];
    dis[n] = rsqrtf(s + 1.f);
  }
  float v = s;
  #pragma unroll
  for (int o = 32; o > 0; o >>= 1) v += __shfl_down(v, o);
  __shared__ float ls[4];
  int lane = threadIdx.x & 63, wid = threadIdx.x >> 6;
  if (lane == 0) ls[wid] = v;
  __syncthreads();
  if (threadIdx.x == 0) atomicAdd(m_out, ls[0] + ls[1] + ls[2] + ls[3]);
}

// ---------- pn: fold dis[src] into csr weight in place: csr_w[j] *= dis[csr_src[j]] ----------
__global__ __launch_bounds__(256) void k_pn(const int* __restrict__ csr_src,
                                            const float* __restrict__ dis,
                                            float* __restrict__ csr_w) {
  int j = blockIdx.x * 256 + threadIdx.x;
  int s = csr_src[j];
  csr_w[j] *= dis[s];
}

// ---------- wprep: WT1[vc][k] = bf16(W[k][c]), vc<256 -> Wc1, vc>=256 -> Wl1 ----------
__global__ __launch_bounds__(256) void k_wprep(const float* __restrict__ Wc,
                                               const float* __restrict__ Wl,
                                               ushort* __restrict__ WT1) {
  int idx = blockIdx.x * 256 + threadIdx.x;   // 16384 total
  int vc = idx >> 5;
  int kq = (idx & 31) * 4;
  const float* W = (vc < HID) ? Wc : Wl;
  int c = vc & (HID - 1);
  ushort4 u;
  u.x = f2bf(W[(size_t)(kq + 0) * HID + c]);
  u.y = f2bf(W[(size_t)(kq + 1) * HID + c]);
  u.z = f2bf(W[(size_t)(kq + 2) * HID + c]);
  u.w = f2bf(W[(size_t)(kq + 3) * HID + c]);
  *(ushort4*)(WT1 + (size_t)vc * F_IN + kq) = u;
}

// ---------- wprep2: WT2[vc][k] = bf16(W2[k][c]), vc<32 -> Wc2 col vc, vc>=32 -> Wl2 col vc-32 ----------
__global__ __launch_bounds__(256) void k_wprep2(const float* __restrict__ Wc,
                                                const float* __restrict__ Wl,
                                                ushort* __restrict__ WT2) {
  int idx = blockIdx.x * 256 + threadIdx.x;   // 4096 total
  int vc = idx >> 6;
  int kq = (idx & 63) * 4;
  const float* W = (vc < 32) ? Wc : Wl;
  int c = vc & 31;
  ushort4 u = make_ushort4(0, 0, 0, 0);
  if (c < KCL) {
    u.x = f2bf(W[(size_t)(kq + 0) * KCL + c]);
    u.y = f2bf(W[(size_t)(kq + 1) * KCL + c]);
    u.z = f2bf(W[(size_t)(kq + 2) * KCL + c]);
    u.w = f2bf(W[(size_t)(kq + 3) * KCL + c]);
  }
  *(ushort4*)(WT2 + (size_t)vc * HID + kq) = u;
}

// ---------- layer-1 dual GEMM via MFMA bf16 (both col-halves per block; x staged once) ----------
__global__ __launch_bounds__(256) void k_gemm1m(const float* __restrict__ x,
                                                const ushort* __restrict__ WT1,
                                                const float* __restrict__ bc,
                                                const float* __restrict__ bl,
                                                const float* __restrict__ dis,
                                                ushort* __restrict__ hconv_bf,
                                                float* __restrict__ base1) {
  __shared__ ushort xs[32 * F_IN];   // 8 KB, XOR-swizzled bf16
  const int t = threadIdx.x;
  const int lane = t & 63, wid = t >> 6;
  const int m0 = blockIdx.x * 32;
  {
    int row = t >> 3, k0 = (t & 7) * 16;
    const float4* xp = (const float4*)(x + (size_t)(m0 + row) * F_IN + k0);
    #pragma unroll
    for (int q = 0; q < 4; ++q) {
      float4 v = xp[q];
      ushort4 u = make_ushort4(f2bf(v.x), f2bf(v.y), f2bf(v.z), f2bf(v.w));
      int k = k0 + q * 4;
      *(ushort4*)&xs[row * F_IN + (k ^ ((row & 7) << 3))] = u;
    }
  }
  __syncthreads();
  const int r0 = lane & 15, r1 = 16 + (lane & 15);
  const int kb = (lane >> 4) * 8;
  bf16x8 A0[4], A1[4];
  #pragma unroll
  for (int ks = 0; ks < 4; ++ks) {
    int k = ks * 32 + kb;
    A0[ks] = *(const bf16x8*)&xs[r0 * F_IN + (k ^ ((r0 & 7) << 3))];
    A1[ks] = *(const bf16x8*)&xs[r1 * F_IN + (k ^ ((r1 & 7) << 3))];
  }
  const int rb = (lane >> 4) * 4;
  #pragma unroll
  for (int cb = 0; cb < 2; ++cb) {
    bf16x8 B[4][4];   // f = cs*2+cf: {C0,C1,L0,L1}
    const int vbase = cb * 128 + wid * 32 + (lane & 15);
    #pragma unroll
    for (int cs = 0; cs < 2; ++cs)
      #pragma unroll
      for (int cf = 0; cf < 2; ++cf)
        #pragma unroll
        for (int ks = 0; ks < 4; ++ks) {
          int vc = cs * HID + vbase + cf * 16;
          B[cs * 2 + cf][ks] = *(const bf16x8*)(WT1 + (size_t)vc * F_IN + ks * 32 + kb);
        }
    f32x4 acc[2][4];
    #pragma unroll
    for (int fm = 0; fm < 2; ++fm)
      #pragma unroll
      for (int f = 0; f < 4; ++f) acc[fm][f] = (f32x4){0.f, 0.f, 0.f, 0.f};
    #pragma unroll
    for (int ks = 0; ks < 4; ++ks) {
      #pragma unroll
      for (int f = 0; f < 4; ++f) {
        acc[0][f] = __builtin_amdgcn_mfma_f32_16x16x32_bf16(A0[ks], B[f][ks], acc[0][f], 0, 0, 0);
        acc[1][f] = __builtin_amdgcn_mfma_f32_16x16x32_bf16(A1[ks], B[f][ks], acc[1][f], 0, 0, 0);
      }
    }
    #pragma unroll
    for (int cf = 0; cf < 2; ++cf) {
      int c = cb * 128 + wid * 32 + cf * 16 + (lane & 15);
      float bcv = bc[c], blv = bl[c];
      #pragma unroll
      for (int fm = 0; fm < 2; ++fm) {
        #pragma unroll
        for (int r = 0; r < 4; ++r) {
          int row = m0 + fm * 16 + rb + r;
          float hc = acc[fm][cf][r];
          float hl = acc[fm][2 + cf][r];
          float d = dis[row];
          hconv_bf[(size_t)row * HID + c] = f2bf(hc);
          base1[(size_t)row * HID + c] = hl + blv + bcv + d * d * hc;
        }
      }
    }
  }
}

// ---------- layer-1 aggregation: h1 = relu(dis_n * sum_e pn*hconv[src] + base1) ----------
__global__ __launch_bounds__(256) void k_agg1(const int* __restrict__ off8,
                                              const int* __restrict__ csr_src,
                                              const float* __restrict__ csr_pn,
                                              const float* __restrict__ dis,
                                              const ushort* __restrict__ hconv_bf,
                                              const float* __restrict__ base1,
                                              ushort* __restrict__ h1b) {
  const int n = blockIdx.x;
  const int t = threadIdx.x;
  const int lane = t & 63, wid = t >> 6;
  const int e0 = off8[(size_t)n * NCOPY];
  const int e1 = off8[(size_t)(n + 1) * NCOPY];
  __shared__ int s_src[256];
  __shared__ float s_pn[256];
  __shared__ float red[4][256];
  float acc0 = 0.f, acc1 = 0.f, acc2 = 0.f, acc3 = 0.f;
  for (int jb = e0; jb < e1; jb += 256) {
    int cn = min(256, e1 - jb);
    __syncthreads();
    if (t < cn) {
      s_src[t] = csr_src[jb + t];
      s_pn[t] = csr_pn[jb + t];
    }
    __syncthreads();
    int j = wid;
    for (; j + 4 < cn; j += 8) {
      int sA = s_src[j];         float nA = s_pn[j];
      int sB = s_src[j + 4];     float nB = s_pn[j + 4];
      ushort4 vA = *(const ushort4*)(hconv_bf + (size_t)sA * HID + lane * 4);
      ushort4 vB = *(const ushort4*)(hconv_bf + (size_t)sB * HID + lane * 4);
      acc0 = fmaf(nA, bf2f(vA.x), acc0); acc1 = fmaf(nA, bf2f(vA.y), acc1);
      acc2 = fmaf(nA, bf2f(vA.z), acc2); acc3 = fmaf(nA, bf2f(vA.w), acc3);
      acc0 = fmaf(nB, bf2f(vB.x), acc0); acc1 = fmaf(nB, bf2f(vB.y), acc1);
      acc2 = fmaf(nB, bf2f(vB.z), acc2); acc3 = fmaf(nB, bf2f(vB.w), acc3);
    }
    if (j < cn) {
      int sA = s_src[j]; float nA = s_pn[j];
      ushort4 vA = *(const ushort4*)(hconv_bf + (size_t)sA * HID + lane * 4);
      acc0 = fmaf(nA, bf2f(vA.x), acc0); acc1 = fmaf(nA, bf2f(vA.y), acc1);
      acc2 = fmaf(nA, bf2f(vA.z), acc2); acc3 = fmaf(nA, bf2f(vA.w), acc3);
    }
  }
  __syncthreads();
  ((float4*)red[wid])[lane] = make_float4(acc0, acc1, acc2, acc3);
  __syncthreads();
  float dn = dis[n];
  float v = dn * (red[0][t] + red[1][t] + red[2][t] + red[3][t]) + base1[(size_t)n * HID + t];
  h1b[(size_t)n * HID + t] = f2bf(fmaxf(v, 0.f));
}

// ---------- layer-2 dual GEMM via MFMA bf16: 64 rows/block, wave owns 16 rows x 4 col-tiles ----------
__global__ __launch_bounds__(256) void k_gemm2m(const ushort* __restrict__ h1b,
                                                const ushort* __restrict__ WT2,
                                                const float* __restrict__ bc,
                                                const float* __restrict__ bl,
                                                const float* __restrict__ dis,
                                                ushort* __restrict__ hconv2p,
                                                float* __restrict__ base2p) {
  __shared__ ushort hs[64 * HID];    // 32 KB, XOR-swizzled bf16
  const int t = threadIdx.x;
  const int lane = t & 63, wid = t >> 6;
  const int n0 = blockIdx.x * 64;
  {
    int row = t >> 2, kq = (t & 3) * 64;
    int gn = n0 + row;
    #pragma unroll
    for (int q = 0; q < 8; ++q) {
      int k = kq + q * 8;
      uint4 u = make_uint4(0, 0, 0, 0);
      if (gn < N_NODES) u = *(const uint4*)(h1b + (size_t)gn * HID + k);
      *(uint4*)&hs[row * HID + (k ^ ((row & 7) << 3))] = u;
    }
  }
  __syncthreads();
  const int lr = wid * 16 + (lane & 15);
  const int kb = (lane >> 4) * 8;
  f32x4 acc[4];
  #pragma unroll
  for (int f = 0; f < 4; ++f) acc[f] = (f32x4){0.f, 0.f, 0.f, 0.f};
  #pragma unroll
  for (int ks = 0; ks < 8; ++ks) {
    int k = ks * 32 + kb;
    bf16x8 A = *(const bf16x8*)&hs[lr * HID + (k ^ ((lr & 7) << 3))];
    #pragma unroll
    for (int f = 0; f < 4; ++f) {
      int vc = f * 16 + (lane & 15);
      bf16x8 B = *(const bf16x8*)(WT2 + (size_t)vc * HID + k);
      acc[f] = __builtin_amdgcn_mfma_f32_16x16x32_bf16(A, B, acc[f], 0, 0, 0);
    }
  }
  const int rb = (lane >> 4) * 4;
  #pragma unroll
  for (int cf = 0; cf < 2; ++cf) {
    int c = cf * 16 + (lane & 15);
    if (c < KCL) {
      float bcv = bc[c], blv = bl[c];
      #pragma unroll
      for (int r = 0; r < 4; ++r) {
        int row = n0 + wid * 16 + rb + r;
        if (row < N_NODES) {
          float hc = acc[cf][r];
          float hl = acc[2 + cf][r];
          float d = dis[row];
          hconv2p[(size_t)row * 32 + c] = f2bf(hc);
          base2p[(size_t)row * 32 + c] = hl + blv + bcv + d * d * hc;
        }
      }
    }
  }
}

// ---------- layer-2 aggregation + softmax + clip + FX(fp32) + FXbp(bf16, stride 32) + colsum ----------
// 2048 blocks (full occupancy); dual accumulator chains keep 2 gathers in flight per half-wave.
__global__ __launch_bounds__(256) void k_agg2(const int* __restrict__ off8,
                                              const int* __restrict__ csr_src,
                                              const float* __restrict__ csr_pn,
                                              const float* __restrict__ dis,
                                              const ushort* __restrict__ hconv2p,
                                              const float* __restrict__ base2p,
                                              float* __restrict__ FX,
                                              ushort* __restrict__ FXbp,
                                              float* __restrict__ scal) {
  const int t = threadIdx.x;
  const int lane = t & 63, wid = t >> 6;
  const int half = lane >> 5, c = lane & 31;
  const int nwaves = gridDim.x * 4;
  const int gw = blockIdx.x * 4 + wid;
  float cs_acc = 0.f;
  for (int n = gw; n < N_NODES; n += nwaves) {
    int e0 = off8[(size_t)n * NCOPY];
    int e1 = off8[(size_t)(n + 1) * NCOPY];
    float accA = 0.f, accB = 0.f;
    int j = e0 + half;
    for (; j + 2 < e1; j += 4) {
      int s0 = csr_src[j];
      int s1 = csr_src[j + 2];
      float p0 = csr_pn[j];
      float p1 = csr_pn[j + 2];
      float v0 = (c < KCL) ? bf2f(hconv2p[(size_t)s0 * 32 + c]) : 0.f;
      float v1 = (c < KCL) ? bf2f(hconv2p[(size_t)s1 * 32 + c]) : 0.f;
      accA = fmaf(p0, v0, accA);
      accB = fmaf(p1, v1, accB);
    }
    if (j < e1) {
      int s0 = csr_src[j];
      float p0 = csr_pn[j];
      float v0 = (c < KCL) ? bf2f(hconv2p[(size_t)s0 * 32 + c]) : 0.f;
      accA = fmaf(p0, v0, accA);
    }
    float acc = accA + accB;
    acc += __shfl(acc, lane ^ 32);
    float out = (c < KCL) ? acc * dis[n] + base2p[(size_t)n * 32 + c] : -1e30f;
    float mx = out;
    #pragma unroll
    for (int o = 16; o > 0; o >>= 1) mx = fmaxf(mx, __shfl_xor(mx, o));
    float p = (c < KCL) ? __expf(out - mx) : 0.f;
    float sum = p;
    #pragma unroll
    for (int o = 16; o > 0; o >>= 1) sum += __shfl_xor(sum, o);
    float fx = p / sum;
    fx = fminf(fmaxf(fx, 1e-9f), 1.f - 1e-9f);
    if (half == 0 && c < KCL) {
      FX[(size_t)n * KCL + c] = fx;
      FXbp[(size_t)n * 32 + c] = f2bf(fx);
    }
    cs_acc += (c < KCL) ? fx : 0.f;
  }
  __shared__ float red_cs[4][32];
  if (half == 0) red_cs[wid][c] = cs_acc;
  __syncthreads();
  if (t < KCL) {
    float a = red_cs[0][t] + red_cs[1][t] + red_cs[2][t] + red_cs[3][t];
    atomicAdd(&scal[2 + t], a);
  }
}

// ---------- connectivity + degree-weighted colsum s over bf16 FX shadow (stride 32) ----------
__global__ __launch_bounds__(256) void k_conn(const int* __restrict__ ei,
                                              const float* __restrict__ w,
                                              const ushort* __restrict__ FXbp,
                                              float* __restrict__ scal) {
  const int t = threadIdx.x;
  const int lane = t & 63, wid = t >> 6;
  const size_t e0 = ((size_t)blockIdx.x * 256 + t) * 4;
  float sv[29];
  #pragma unroll
  for (int k = 0; k < 29; ++k) sv[k] = 0.f;
  float conn = 0.f;
  int4 rr = *(const int4*)(ei + e0);
  int4 cc = *(const int4*)(ei + N_EDGES + e0);
  float4 ww = *(const float4*)(w + e0);
  const int rA[4] = {rr.x, rr.y, rr.z, rr.w};
  const int cA[4] = {cc.x, cc.y, cc.z, cc.w};
  const float wA[4] = {ww.x, ww.y, ww.z, ww.w};
  #pragma unroll
  for (int q = 0; q < 4; ++q) {
    int r = rA[q], cN = cA[q];
    float wv = wA[q];
    const uint* fr = (const uint*)FXbp + (size_t)r * 16;
    const uint* fc = (const uint*)FXbp + (size_t)cN * 16;
    float dot = 0.f;
    #pragma unroll
    for (int k = 0; k < 14; ++k) {
      uint ua = fr[k], ub = fc[k];
      float a0 = bf2f((ushort)(ua & 0xFFFF)), a1 = bf2f_hi(ua);
      float b0 = bf2f((ushort)(ub & 0xFFFF)), b1 = bf2f_hi(ub);
      dot += a0 * b0 + a1 * b1;
      sv[2 * k] = fmaf(wv, a0, sv[2 * k]);
      sv[2 * k + 1] = fmaf(wv, a1, sv[2 * k + 1]);
    }
    float a28 = bf2f((ushort)(fr[14] & 0xFFFF));
    float b28 = bf2f((ushort)(fc[14] & 0xFFFF));
    dot += a28 * b28;
    sv[28] = fmaf(wv, a28, sv[28]);
    conn = fmaf(wv, dot, conn);
  }
  __shared__ float red[4][30];
  #pragma unroll
  for (int i = 0; i < 30; ++i) {
    float v = (i < 29) ? sv[i] : conn;
    #pragma unroll
    for (int o = 32; o > 0; o >>= 1) v += __shfl_down(v, o);
    if (lane == 0) red[wid][i] = v;
  }
  __syncthreads();
  if (t < 30) {
    float s = red[0][t] + red[1][t] + red[2][t] + red[3][t];
    atomicAdd(t == 29 ? &scal[1] : &scal[32 + t], s);
  }
}

// ---------- final scalar loss ----------
__global__ void k_finalize(const float* __restrict__ scal, float* __restrict__ out_loss) {
  if (threadIdx.x == 0 && blockIdx.x == 0) {
    float m = scal[0], conn = scal[1];
    float ss = 0.f;
    for (int k = 0; k < KCL - 1; ++k) { float s = scal[32 + k]; ss += s * s; }
    float cs2 = 0.f;
    for (int k = 0; k < KCL; ++k) { float cv = scal[2 + k]; cs2 += cv * cv; }
    float avg = ss / (2.f * m);
    float modularity = -(conn - avg) / (2.f * m);
    float reg = sqrtf(cs2 + 1e-9f) * sqrtf((float)KCL) / (float)N_NODES - 1.f;
    out_loss[0] = modularity + 0.01f * reg;
  }
}

extern "C" void kernel_launch(void* const* d_in, const int* in_sizes, int n_in,
                              void* d_out, int out_size, void* d_ws, size_t ws_size,
                              hipStream_t stream) {
  const float* x   = (const float*)d_in[0];
  const int*   ei  = (const int*)d_in[1];
  const float* ea  = (const float*)d_in[2];
  const float* Wc1 = (const float*)d_in[3];
  const float* bc1 = (const float*)d_in[4];
  const float* Wl1 = (const float*)d_in[5];
  const float* bl1 = (const float*)d_in[6];
  const float* Wc2 = (const float*)d_in[7];
  const float* bc2 = (const float*)d_in[8];
  const float* Wl2 = (const float*)d_in[9];
  const float* bl2 = (const float*)d_in[10];
  float* out = (float*)d_out;

  float* ws = (float*)d_ws;
  size_t o = 0;
  int*   cnt8   = (int*)(ws + o); o += (size_t)NCOPY * N_NODES;  // zeroed
  float* scal   = ws + o; o += 64;                               // zeroed
  size_t zero_floats = o;
  int*   off8   = (int*)(ws + o); o += (size_t)N_NODES * NCOPY + 8;
  int*   blocktot = (int*)(ws + o); o += 128;
  int*   blockoff = (int*)(ws + o); o += 128;
  float* dis    = ws + o; o += N_NODES;
  int*   csr_src= (int*)(ws + o); o += N_EDGES;
  float* csr_w  = ws + o; o += N_EDGES;   // becomes csr_pn in place after k_pn
  ushort* WT1   = (ushort*)(ws + o); o += (size_t)512 * F_IN / 2;
  ushort* WT2   = (ushort*)(ws + o); o += (size_t)64 * HID / 2;
  ushort* hconv_bf = (ushort*)(ws + o); o += (size_t)N_NODES * HID / 2;
  float* base1  = ws + o; o += (size_t)N_NODES * HID;
  ushort* h1b   = (ushort*)(ws + o); o += (size_t)N_NODES * HID / 2;
  ushort* hconv2p = (ushort*)(ws + o); o += (size_t)N_NODES * 32 / 2;
  float* base2p = ws + o; o += (size_t)N_NODES * 32;
  o += 64;  // slack
  if (ws_size < o * sizeof(float)) return;  // insufficient workspace — bail safely

  ushort* FXbp = hconv_bf;   // alias: dead after k_agg1

  hipMemsetAsync(d_ws, 0, zero_floats * sizeof(float), stream);

  k_cnt8<<<N_EDGES / 256, 256, 0, stream>>>(ei, cnt8);
  k_scanA<<<98, 1024, 0, stream>>>(cnt8, off8, blocktot);
  k_scanB<<<1, 64, 0, stream>>>(blocktot, blockoff);
  k_scanC<<<(N_NODES * NCOPY + 256) / 256, 256, 0, stream>>>(off8, blockoff);
  k_csrfill8<<<N_EDGES / 256, 256, 0, stream>>>(ei, ea, cnt8, off8, csr_src, csr_w);
  k_degdis<<<(N_NODES + 255) / 256, 256, 0, stream>>>(off8, csr_w, dis, scal);
  k_pn<<<N_EDGES / 256, 256, 0, stream>>>(csr_src, dis, csr_w);
  k_wprep<<<64, 256, 0, stream>>>(Wc1, Wl1, WT1);
  k_wprep2<<<16, 256, 0, stream>>>(Wc2, Wl2, WT2);
  k_gemm1m<<<N_NODES / 32, 256, 0, stream>>>(x, WT1, bc1, bl1, dis, hconv_bf, base1);
  k_agg1<<<N_NODES, 256, 0, stream>>>(off8, csr_src, csr_w, dis, hconv_bf, base1, h1b);
  k_gemm2m<<<(N_NODES + 63) / 64, 256, 0, stream>>>(h1b, WT2, bc2, bl2, dis, hconv2p, base2p);
  k_agg2<<<2048, 256, 0, stream>>>(off8, csr_src, csr_w, dis, hconv2p, base2p, out, FXbp, scal);
  k_conn<<<N_EDGES / 1024, 256, 0, stream>>>(ei, ea, FXbp, scal);
  k_finalize<<<1, 64, 0, stream>>>(scal, out + (size_t)N_NODES * KCL);
}

// Round 7
// 888.825 us; speedup vs baseline: 2.4719x; 1.1335x over previous
//
#include <hip/hip_runtime.h>
#include <hip/hip_bf16.h>
#include <math.h>

#define N_NODES 100000
#define N_EDGES 3200000
#define F_IN 128
#define HID 256
#define KCL 30
#define NCOPY 8

typedef unsigned int uint;
typedef unsigned short ushort;
typedef unsigned char uchar;
typedef __attribute__((ext_vector_type(8))) short bf16x8;
typedef __attribute__((ext_vector_type(4))) float f32x4;
typedef __attribute__((ext_vector_type(2))) float f32x2;

static __device__ __forceinline__ float bf2f(ushort u) {
  return __uint_as_float(((uint)u) << 16);
}
static __device__ __forceinline__ float bf2f_hi(uint u) {
  return __uint_as_float(u & 0xFFFF0000u);
}
static __device__ __forceinline__ ushort f2bf(float f) {
  uint u = __float_as_uint(f);
  uint r = (u + 0x7FFF + ((u >> 16) & 1)) >> 16;   // round-to-nearest-even
  return (ushort)r;
}

// ---- fp8 e4m3 (OCP) encode/decode: HW cvt if available, software fallback ----
static __device__ __forceinline__ uchar f2fp8(float f) {
#if __has_builtin(__builtin_amdgcn_cvt_pk_fp8_f32)
  return (uchar)(__builtin_amdgcn_cvt_pk_fp8_f32(f, f, 0, false) & 0xFF);
#else
  uint u = __float_as_uint(f);
  uint s = (u >> 24) & 0x80u;
  float a = fabsf(f);
  if (a >= 448.f) return (uchar)(s | 0x7E);
  if (a < 0.015625f) {
    int q = (int)rintf(a * 512.f);
    return (uchar)(s | (q > 8 ? 8 : q));
  }
  int e = ((int)((u >> 23) & 0xFF)) - 127;
  float step = __uint_as_float((uint)(127 + e - 3) << 23);
  int q = (int)rintf(a / step);
  if (q == 16) { e += 1; q = 8; }
  return (uchar)(s | ((e + 7) << 3) | (q - 8));
#endif
}
static __device__ __forceinline__ float fp82f_sw(uchar b) {
  uint s = ((uint)(b & 0x80u)) << 24;
  uint em = b & 0x7Fu;
  float mag;
  if ((em >> 3) == 0) mag = (float)em * 0.001953125f;
  else mag = __uint_as_float((((em >> 3) + 120) << 23) | ((em & 7u) << 20));
  return __uint_as_float(s | __float_as_uint(mag));
}
// decode 4 packed fp8 (one dword) -> 4 floats
static __device__ __forceinline__ void fp8x4_dec(uint u, float* o) {
#if __has_builtin(__builtin_amdgcn_cvt_pk_f32_fp8)
  f32x2 lo = __builtin_amdgcn_cvt_pk_f32_fp8((int)u, false);
  f32x2 hi = __builtin_amdgcn_cvt_pk_f32_fp8((int)u, true);
  o[0] = lo.x; o[1] = lo.y; o[2] = hi.x; o[3] = hi.y;
#else
  o[0] = fp82f_sw(u & 0xFF); o[1] = fp82f_sw((u >> 8) & 0xFF);
  o[2] = fp82f_sw((u >> 16) & 0xFF); o[3] = fp82f_sw((u >> 24) & 0xFF);
#endif
}

// scal layout: [0]=m, [1]=connectivity, [2..31]=colsum(30), [32..60]=svec(29)

// ---------- cnt8: XCD-privatized edge-count histogram (keyed by col) ----------
__global__ __launch_bounds__(256) void k_cnt8(const int* __restrict__ ei,
                                              int* __restrict__ cnt8) {
  int e = blockIdx.x * 256 + threadIdx.x;
  int g = blockIdx.x & (NCOPY - 1);
  int c = ei[N_EDGES + e];
  atomicAdd(cnt8 + (size_t)g * N_NODES + c, 1);
}

// ---------- scanA: per-1024-node block scan of 8-copy counts ----------
__global__ __launch_bounds__(1024) void k_scanA(const int* __restrict__ cnt8,
                                                int* __restrict__ off8,
                                                int* __restrict__ blocktot) {
  __shared__ int wsum[16];
  const int t = threadIdx.x;
  const int lane = t & 63, wid = t >> 6;
  int node = blockIdx.x * 1024 + t;
  int v[NCOPY];
  int tot = 0;
  if (node < N_NODES) {
    #pragma unroll
    for (int g = 0; g < NCOPY; ++g) {
      int x = cnt8[(size_t)g * N_NODES + node];
      v[g] = tot;
      tot += x;
    }
  } else {
    #pragma unroll
    for (int g = 0; g < NCOPY; ++g) v[g] = 0;
  }
  int x = tot;
  #pragma unroll
  for (int o = 1; o < 64; o <<= 1) {
    int y = __shfl_up(x, o);
    if (lane >= o) x += y;
  }
  if (lane == 63) wsum[wid] = x;
  __syncthreads();
  if (t < 16) {
    int s = wsum[t];
    #pragma unroll
    for (int o = 1; o < 16; o <<= 1) {
      int y = __shfl_up(s, o);
      if (t >= o) s += y;
    }
    wsum[t] = s;
  }
  __syncthreads();
  int excl = (wid ? wsum[wid - 1] : 0) + x - tot;
  if (node < N_NODES) {
    #pragma unroll
    for (int g = 0; g < NCOPY; ++g) off8[(size_t)node * NCOPY + g] = excl + v[g];
  }
  if (t == 0) blocktot[blockIdx.x] = wsum[15];
}

// ---------- scanB ----------
__global__ void k_scanB(const int* __restrict__ blocktot, int* __restrict__ blockoff) {
  if (threadIdx.x == 0 && blockIdx.x == 0) {
    int acc = 0;
    for (int b = 0; b < 98; ++b) { blockoff[b] = acc; acc += blocktot[b]; }
  }
}

// ---------- scanC ----------
__global__ __launch_bounds__(256) void k_scanC(int* __restrict__ off8,
                                               const int* __restrict__ blockoff) {
  int idx = blockIdx.x * 256 + threadIdx.x;
  if (idx > N_NODES * NCOPY) return;
  if (idx == N_NODES * NCOPY) { off8[idx] = N_EDGES; return; }
  off8[idx] += blockoff[idx >> 13];
}

// ---------- csrfill8: scatter packed (src, w) int2 — one random line per edge ----------
__global__ __launch_bounds__(256) void k_csrfill8(const int* __restrict__ ei,
                                                  const float* __restrict__ w,
                                                  int* __restrict__ cnt8,
                                                  const int* __restrict__ off8,
                                                  int2* __restrict__ csr) {
  int e = blockIdx.x * 256 + threadIdx.x;
  int g = blockIdx.x & (NCOPY - 1);
  int r = ei[e], c = ei[N_EDGES + e];
  int idx = atomicSub(cnt8 + (size_t)g * N_NODES + c, 1) - 1;
  int pos = off8[(size_t)c * NCOPY + g] + idx;
  csr[pos] = make_int2(r, __float_as_int(w[e]));
}

// ---------- degdis ----------
__global__ __launch_bounds__(256) void k_degdis(const int* __restrict__ off8,
                                                const int2* __restrict__ csr,
                                                float* __restrict__ dis,
                                                float* __restrict__ m_out) {
  int n = blockIdx.x * 256 + threadIdx.x;
  float s = 0.f;
  if (n < N_NODES) {
    int e0 = off8[(size_t)n * NCOPY];
    int e1 = off8[(size_t)(n + 1) * NCOPY];
    for (int j = e0; j < e1; ++j) s += __int_as_float(csr[j].y);
    dis[n] = rsqrtf(s + 1.f);
  }
  float v = s;
  #pragma unroll
  for (int o = 32; o > 0; o >>= 1) v += __shfl_down(v, o);
  __shared__ float ls[4];
  int lane = threadIdx.x & 63, wid = threadIdx.x >> 6;
  if (lane == 0) ls[wid] = v;
  __syncthreads();
  if (threadIdx.x == 0) atomicAdd(m_out, ls[0] + ls[1] + ls[2] + ls[3]);
}

// ---------- pn: fold dis[src] into csr.y in place ----------
__global__ __launch_bounds__(256) void k_pn(int2* __restrict__ csr,
                                            const float* __restrict__ dis) {
  int j = blockIdx.x * 256 + threadIdx.x;
  int2 e = csr[j];
  csr[j] = make_int2(e.x, __float_as_int(__int_as_float(e.y) * dis[e.x]));
}

// ---------- wprep ----------
__global__ __launch_bounds__(256) void k_wprep(const float* __restrict__ Wc,
                                               const float* __restrict__ Wl,
                                               ushort* __restrict__ WT1) {
  int idx = blockIdx.x * 256 + threadIdx.x;
  int vc = idx >> 5;
  int kq = (idx & 31) * 4;
  const float* W = (vc < HID) ? Wc : Wl;
  int c = vc & (HID - 1);
  ushort4 u;
  u.x = f2bf(W[(size_t)(kq + 0) * HID + c]);
  u.y = f2bf(W[(size_t)(kq + 1) * HID + c]);
  u.z = f2bf(W[(size_t)(kq + 2) * HID + c]);
  u.w = f2bf(W[(size_t)(kq + 3) * HID + c]);
  *(ushort4*)(WT1 + (size_t)vc * F_IN + kq) = u;
}

// ---------- wprep2 ----------
__global__ __launch_bounds__(256) void k_wprep2(const float* __restrict__ Wc,
                                                const float* __restrict__ Wl,
                                                ushort* __restrict__ WT2) {
  int idx = blockIdx.x * 256 + threadIdx.x;
  int vc = idx >> 6;
  int kq = (idx & 63) * 4;
  const float* W = (vc < 32) ? Wc : Wl;
  int c = vc & 31;
  ushort4 u = make_ushort4(0, 0, 0, 0);
  if (c < KCL) {
    u.x = f2bf(W[(size_t)(kq + 0) * KCL + c]);
    u.y = f2bf(W[(size_t)(kq + 1) * KCL + c]);
    u.z = f2bf(W[(size_t)(kq + 2) * KCL + c]);
    u.w = f2bf(W[(size_t)(kq + 3) * KCL + c]);
  }
  *(ushort4*)(WT2 + (size_t)vc * HID + kq) = u;
}

// ---------- layer-1 dual GEMM via MFMA bf16; hconv out in fp8 (LDS repack), base1 out bf16 ----------
__global__ __launch_bounds__(256) void k_gemm1m(const float* __restrict__ x,
                                                const ushort* __restrict__ WT1,
                                                const float* __restrict__ bc,
                                                const float* __restrict__ bl,
                                                const float* __restrict__ dis,
                                                uchar* __restrict__ hconv_f8,
                                                ushort* __restrict__ base1b) {
  __shared__ ushort xs[32 * F_IN];   // 8 KB: bf16 x-tile, then reused as fp8 [32][256] tile
  uchar* xs8 = (uchar*)xs;
  const int t = threadIdx.x;
  const int lane = t & 63, wid = t >> 6;
  const int m0 = blockIdx.x * 32;
  {
    int row = t >> 3, k0 = (t & 7) * 16;
    const float4* xp = (const float4*)(x + (size_t)(m0 + row) * F_IN + k0);
    #pragma unroll
    for (int q = 0; q < 4; ++q) {
      float4 v = xp[q];
      ushort4 u = make_ushort4(f2bf(v.x), f2bf(v.y), f2bf(v.z), f2bf(v.w));
      int k = k0 + q * 4;
      *(ushort4*)&xs[row * F_IN + (k ^ ((row & 7) << 3))] = u;
    }
  }
  __syncthreads();
  const int r0 = lane & 15, r1 = 16 + (lane & 15);
  const int kb = (lane >> 4) * 8;
  bf16x8 A0[4], A1[4];
  #pragma unroll
  for (int ks = 0; ks < 4; ++ks) {
    int k = ks * 32 + kb;
    A0[ks] = *(const bf16x8*)&xs[r0 * F_IN + (k ^ ((r0 & 7) << 3))];
    A1[ks] = *(const bf16x8*)&xs[r1 * F_IN + (k ^ ((r1 & 7) << 3))];
  }
  __syncthreads();   // all waves done reading xs; safe to overwrite with fp8 bytes
  const int rb = (lane >> 4) * 4;
  #pragma unroll
  for (int cb = 0; cb < 2; ++cb) {
    bf16x8 B[4][4];   // f = cs*2+cf: {C0,C1,L0,L1}
    const int vbase = cb * 128 + wid * 32 + (lane & 15);
    #pragma unroll
    for (int cs = 0; cs < 2; ++cs)
      #pragma unroll
      for (int cf = 0; cf < 2; ++cf)
        #pragma unroll
        for (int ks = 0; ks < 4; ++ks) {
          int vc = cs * HID + vbase + cf * 16;
          B[cs * 2 + cf][ks] = *(const bf16x8*)(WT1 + (size_t)vc * F_IN + ks * 32 + kb);
        }
    f32x4 acc[2][4];
    #pragma unroll
    for (int fm = 0; fm < 2; ++fm)
      #pragma unroll
      for (int f = 0; f < 4; ++f) acc[fm][f] = (f32x4){0.f, 0.f, 0.f, 0.f};
    #pragma unroll
    for (int ks = 0; ks < 4; ++ks) {
      #pragma unroll
      for (int f = 0; f < 4; ++f) {
        acc[0][f] = __builtin_amdgcn_mfma_f32_16x16x32_bf16(A0[ks], B[f][ks], acc[0][f], 0, 0, 0);
        acc[1][f] = __builtin_amdgcn_mfma_f32_16x16x32_bf16(A1[ks], B[f][ks], acc[1][f], 0, 0, 0);
      }
    }
    #pragma unroll
    for (int cf = 0; cf < 2; ++cf) {
      int c = cb * 128 + wid * 32 + cf * 16 + (lane & 15);
      float bcv = bc[c], blv = bl[c];
      #pragma unroll
      for (int fm = 0; fm < 2; ++fm) {
        #pragma unroll
        for (int r = 0; r < 4; ++r) {
          int lrow = fm * 16 + rb + r;
          int row = m0 + lrow;
          float hc = acc[fm][cf][r];
          float hl = acc[fm][2 + cf][r];
          float d = dis[row];
          xs8[lrow * 256 + c] = f2fp8(hc);
          base1b[(size_t)row * HID + c] = f2bf(hl + blv + bcv + d * d * hc);
        }
      }
    }
  }
  __syncthreads();
  // coalesced copy-out of the fp8 tile: thread t -> row t>>3, 32 B at col (t&7)*32
  {
    int row = t >> 3, c0 = (t & 7) * 32;
    uint4 a = *(const uint4*)&xs8[row * 256 + c0];
    uint4 b = *(const uint4*)&xs8[row * 256 + c0 + 16];
    uchar* dst = hconv_f8 + (size_t)(m0 + row) * 256 + c0;
    *(uint4*)dst = a;
    *(uint4*)(dst + 16) = b;
  }
}

// ---------- layer-1 aggregation over fp8 hconv: h1 = relu(dis_n * sum pn*hconv[src] + base1) ----------
__global__ __launch_bounds__(256) void k_agg1(const int* __restrict__ off8,
                                              const int2* __restrict__ csr,
                                              const uint* __restrict__ hconv_u32,
                                              const ushort* __restrict__ base1b,
                                              const float* __restrict__ dis,
                                              ushort* __restrict__ h1b) {
  const int n = blockIdx.x;
  const int t = threadIdx.x;
  const int lane = t & 63, wid = t >> 6;
  const int e0 = off8[(size_t)n * NCOPY];
  const int e1 = off8[(size_t)(n + 1) * NCOPY];
  __shared__ int2 s_e[256];
  __shared__ float red[4][256];
  float acc0 = 0.f, acc1 = 0.f, acc2 = 0.f, acc3 = 0.f;
  for (int jb = e0; jb < e1; jb += 256) {
    int cn = min(256, e1 - jb);
    __syncthreads();
    if (t < cn) s_e[t] = csr[jb + t];
    __syncthreads();
    int j = wid;
    for (; j + 4 < cn; j += 8) {
      int2 eA = s_e[j];
      int2 eB = s_e[j + 4];
      float nA = __int_as_float(eA.y);
      float nB = __int_as_float(eB.y);
      uint uA = hconv_u32[(size_t)eA.x * 64 + lane];
      uint uB = hconv_u32[(size_t)eB.x * 64 + lane];
      float vA[4], vB[4];
      fp8x4_dec(uA, vA);
      fp8x4_dec(uB, vB);
      acc0 = fmaf(nA, vA[0], acc0); acc1 = fmaf(nA, vA[1], acc1);
      acc2 = fmaf(nA, vA[2], acc2); acc3 = fmaf(nA, vA[3], acc3);
      acc0 = fmaf(nB, vB[0], acc0); acc1 = fmaf(nB, vB[1], acc1);
      acc2 = fmaf(nB, vB[2], acc2); acc3 = fmaf(nB, vB[3], acc3);
    }
    if (j < cn) {
      int2 eA = s_e[j];
      float nA = __int_as_float(eA.y);
      uint uA = hconv_u32[(size_t)eA.x * 64 + lane];
      float vA[4];
      fp8x4_dec(uA, vA);
      acc0 = fmaf(nA, vA[0], acc0); acc1 = fmaf(nA, vA[1], acc1);
      acc2 = fmaf(nA, vA[2], acc2); acc3 = fmaf(nA, vA[3], acc3);
    }
  }
  __syncthreads();
  ((float4*)red[wid])[lane] = make_float4(acc0, acc1, acc2, acc3);
  __syncthreads();
  float dn = dis[n];
  float v = dn * (red[0][t] + red[1][t] + red[2][t] + red[3][t]) + bf2f(base1b[(size_t)n * HID + t]);
  h1b[(size_t)n * HID + t] = f2bf(fmaxf(v, 0.f));
}

// ---------- layer-2 dual GEMM via MFMA bf16 ----------
__global__ __launch_bounds__(256) void k_gemm2m(const ushort* __restrict__ h1b,
                                                const ushort* __restrict__ WT2,
                                                const float* __restrict__ bc,
                                                const float* __restrict__ bl,
                                                const float* __restrict__ dis,
                                                ushort* __restrict__ hconv2p,
                                                float* __restrict__ base2p) {
  __shared__ ushort hs[64 * HID];    // 32 KB, XOR-swizzled bf16
  const int t = threadIdx.x;
  const int lane = t & 63, wid = t >> 6;
  const int n0 = blockIdx.x * 64;
  {
    int row = t >> 2, kq = (t & 3) * 64;
    int gn = n0 + row;
    #pragma unroll
    for (int q = 0; q < 8; ++q) {
      int k = kq + q * 8;
      uint4 u = make_uint4(0, 0, 0, 0);
      if (gn < N_NODES) u = *(const uint4*)(h1b + (size_t)gn * HID + k);
      *(uint4*)&hs[row * HID + (k ^ ((row & 7) << 3))] = u;
    }
  }
  __syncthreads();
  const int lr = wid * 16 + (lane & 15);
  const int kb = (lane >> 4) * 8;
  f32x4 acc[4];
  #pragma unroll
  for (int f = 0; f < 4; ++f) acc[f] = (f32x4){0.f, 0.f, 0.f, 0.f};
  #pragma unroll
  for (int ks = 0; ks < 8; ++ks) {
    int k = ks * 32 + kb;
    bf16x8 A = *(const bf16x8*)&hs[lr * HID + (k ^ ((lr & 7) << 3))];
    #pragma unroll
    for (int f = 0; f < 4; ++f) {
      int vc = f * 16 + (lane & 15);
      bf16x8 B = *(const bf16x8*)(WT2 + (size_t)vc * HID + k);
      acc[f] = __builtin_amdgcn_mfma_f32_16x16x32_bf16(A, B, acc[f], 0, 0, 0);
    }
  }
  const int rb = (lane >> 4) * 4;
  #pragma unroll
  for (int cf = 0; cf < 2; ++cf) {
    int c = cf * 16 + (lane & 15);
    if (c < KCL) {
      float bcv = bc[c], blv = bl[c];
      #pragma unroll
      for (int r = 0; r < 4; ++r) {
        int row = n0 + wid * 16 + rb + r;
        if (row < N_NODES) {
          float hc = acc[cf][r];
          float hl = acc[2 + cf][r];
          float d = dis[row];
          hconv2p[(size_t)row * 32 + c] = f2bf(hc);
          base2p[(size_t)row * 32 + c] = hl + blv + bcv + d * d * hc;
        }
      }
    }
  }
}

// ---------- layer-2 aggregation + softmax + FX(fp32) + FXbp(bf16, stride 32) + colsum ----------
__global__ __launch_bounds__(256) void k_agg2(const int* __restrict__ off8,
                                              const int2* __restrict__ csr,
                                              const float* __restrict__ dis,
                                              const ushort* __restrict__ hconv2p,
                                              const float* __restrict__ base2p,
                                              float* __restrict__ FX,
                                              ushort* __restrict__ FXbp,
                                              float* __restrict__ scal) {
  const int t = threadIdx.x;
  const int lane = t & 63, wid = t >> 6;
  const int half = lane >> 5, c = lane & 31;
  const int nwaves = gridDim.x * 4;
  const int gw = blockIdx.x * 4 + wid;
  float cs_acc = 0.f;
  for (int n = gw; n < N_NODES; n += nwaves) {
    int e0 = off8[(size_t)n * NCOPY];
    int e1 = off8[(size_t)(n + 1) * NCOPY];
    float accA = 0.f, accB = 0.f;
    int j = e0 + half;
    for (; j + 2 < e1; j += 4) {
      int2 eA = csr[j];
      int2 eB = csr[j + 2];
      float p0 = __int_as_float(eA.y);
      float p1 = __int_as_float(eB.y);
      float v0 = (c < KCL) ? bf2f(hconv2p[(size_t)eA.x * 32 + c]) : 0.f;
      float v1 = (c < KCL) ? bf2f(hconv2p[(size_t)eB.x * 32 + c]) : 0.f;
      accA = fmaf(p0, v0, accA);
      accB = fmaf(p1, v1, accB);
    }
    if (j < e1) {
      int2 eA = csr[j];
      float p0 = __int_as_float(eA.y);
      float v0 = (c < KCL) ? bf2f(hconv2p[(size_t)eA.x * 32 + c]) : 0.f;
      accA = fmaf(p0, v0, accA);
    }
    float acc = accA + accB;
    acc += __shfl(acc, lane ^ 32);
    float out = (c < KCL) ? acc * dis[n] + base2p[(size_t)n * 32 + c] : -1e30f;
    float mx = out;
    #pragma unroll
    for (int o = 16; o > 0; o >>= 1) mx = fmaxf(mx, __shfl_xor(mx, o));
    float p = (c < KCL) ? __expf(out - mx) : 0.f;
    float sum = p;
    #pragma unroll
    for (int o = 16; o > 0; o >>= 1) sum += __shfl_xor(sum, o);
    float fx = p / sum;
    fx = fminf(fmaxf(fx, 1e-9f), 1.f - 1e-9f);
    if (half == 0 && c < KCL) {
      FX[(size_t)n * KCL + c] = fx;
      FXbp[(size_t)n * 32 + c] = f2bf(fx);
    }
    cs_acc += (c < KCL) ? fx : 0.f;
  }
  __shared__ float red_cs[4][32];
  if (half == 0) red_cs[wid][c] = cs_acc;
  __syncthreads();
  if (t < KCL) {
    float a = red_cs[0][t] + red_cs[1][t] + red_cs[2][t] + red_cs[3][t];
    atomicAdd(&scal[2 + t], a);
  }
}

// ---------- connectivity + degree-weighted colsum over bf16 FX shadow (stride 32) ----------
__global__ __launch_bounds__(256) void k_conn(const int* __restrict__ ei,
                                              const float* __restrict__ w,
                                              const ushort* __restrict__ FXbp,
                                              float* __restrict__ scal) {
  const int t = threadIdx.x;
  const int lane = t & 63, wid = t >> 6;
  const size_t e0 = ((size_t)blockIdx.x * 256 + t) * 4;
  float sv[29];
  #pragma unroll
  for (int k = 0; k < 29; ++k) sv[k] = 0.f;
  float conn = 0.f;
  int4 rr = *(const int4*)(ei + e0);
  int4 cc = *(const int4*)(ei + N_EDGES + e0);
  float4 ww = *(const float4*)(w + e0);
  const int rA[4] = {rr.x, rr.y, rr.z, rr.w};
  const int cA[4] = {cc.x, cc.y, cc.z, cc.w};
  const float wA[4] = {ww.x, ww.y, ww.z, ww.w};
  #pragma unroll
  for (int q = 0; q < 4; ++q) {
    int r = rA[q], cN = cA[q];
    float wv = wA[q];
    const uint* fr = (const uint*)FXbp + (size_t)r * 16;
    const uint* fc = (const uint*)FXbp + (size_t)cN * 16;
    float dot = 0.f;
    #pragma unroll
    for (int k = 0; k < 14; ++k) {
      uint ua = fr[k], ub = fc[k];
      float a0 = bf2f((ushort)(ua & 0xFFFF)), a1 = bf2f_hi(ua);
      float b0 = bf2f((ushort)(ub & 0xFFFF)), b1 = bf2f_hi(ub);
      dot += a0 * b0 + a1 * b1;
      sv[2 * k] = fmaf(wv, a0, sv[2 * k]);
      sv[2 * k + 1] = fmaf(wv, a1, sv[2 * k + 1]);
    }
    float a28 = bf2f((ushort)(fr[14] & 0xFFFF));
    float b28 = bf2f((ushort)(fc[14] & 0xFFFF));
    dot += a28 * b28;
    sv[28] = fmaf(wv, a28, sv[28]);
    conn = fmaf(wv, dot, conn);
  }
  __shared__ float red[4][30];
  #pragma unroll
  for (int i = 0; i < 30; ++i) {
    float v = (i < 29) ? sv[i] : conn;
    #pragma unroll
    for (int o = 32; o > 0; o >>= 1) v += __shfl_down(v, o);
    if (lane == 0) red[wid][i] = v;
  }
  __syncthreads();
  if (t < 30) {
    float s = red[0][t] + red[1][t] + red[2][t] + red[3][t];
    atomicAdd(t == 29 ? &scal[1] : &scal[32 + t], s);
  }
}

// ---------- final scalar loss ----------
__global__ void k_finalize(const float* __restrict__ scal, float* __restrict__ out_loss) {
  if (threadIdx.x == 0 && blockIdx.x == 0) {
    float m = scal[0], conn = scal[1];
    float ss = 0.f;
    for (int k = 0; k < KCL - 1; ++k) { float s = scal[32 + k]; ss += s * s; }
    float cs2 = 0.f;
    for (int k = 0; k < KCL; ++k) { float cv = scal[2 + k]; cs2 += cv * cv; }
    float avg = ss / (2.f * m);
    float modularity = -(conn - avg) / (2.f * m);
    float reg = sqrtf(cs2 + 1e-9f) * sqrtf((float)KCL) / (float)N_NODES - 1.f;
    out_loss[0] = modularity + 0.01f * reg;
  }
}

extern "C" void kernel_launch(void* const* d_in, const int* in_sizes, int n_in,
                              void* d_out, int out_size, void* d_ws, size_t ws_size,
                              hipStream_t stream) {
  const float* x   = (const float*)d_in[0];
  const int*   ei  = (const int*)d_in[1];
  const float* ea  = (const float*)d_in[2];
  const float* Wc1 = (const float*)d_in[3];
  const float* bc1 = (const float*)d_in[4];
  const float* Wl1 = (const float*)d_in[5];
  const float* bl1 = (const float*)d_in[6];
  const float* Wc2 = (const float*)d_in[7];
  const float* bc2 = (const float*)d_in[8];
  const float* Wl2 = (const float*)d_in[9];
  const float* bl2 = (const float*)d_in[10];
  float* out = (float*)d_out;

  float* ws = (float*)d_ws;
  size_t o = 0;
  int*   cnt8   = (int*)(ws + o); o += (size_t)NCOPY * N_NODES;  // zeroed
  float* scal   = ws + o; o += 64;                               // zeroed
  size_t zero_floats = o;
  int*   off8   = (int*)(ws + o); o += (size_t)N_NODES * NCOPY + 8;
  int*   blocktot = (int*)(ws + o); o += 128;
  int*   blockoff = (int*)(ws + o); o += 128;
  float* dis    = ws + o; o += N_NODES;
  int2*  csr    = (int2*)(ws + o); o += (size_t)N_EDGES * 2;     // packed (src, w->pn)
  ushort* WT1   = (ushort*)(ws + o); o += (size_t)512 * F_IN / 2;
  ushort* WT2   = (ushort*)(ws + o); o += (size_t)64 * HID / 2;
  uchar* hconv_f8 = (uchar*)(ws + o); o += (size_t)N_NODES * HID / 4;
  ushort* base1b = (ushort*)(ws + o); o += (size_t)N_NODES * HID / 2;
  ushort* h1b   = (ushort*)(ws + o); o += (size_t)N_NODES * HID / 2;
  ushort* hconv2p = (ushort*)(ws + o); o += (size_t)N_NODES * 32 / 2;
  float* base2p = ws + o; o += (size_t)N_NODES * 32;
  o += 64;  // slack
  if (ws_size < o * sizeof(float)) return;  // insufficient workspace — bail safely

  ushort* FXbp = (ushort*)hconv_f8;   // alias: dead after k_agg1 (6.4 MB needed < 25.6 MB)

  hipMemsetAsync(d_ws, 0, zero_floats * sizeof(float), stream);

  k_cnt8<<<N_EDGES / 256, 256, 0, stream>>>(ei, cnt8);
  k_scanA<<<98, 1024, 0, stream>>>(cnt8, off8, blocktot);
  k_scanB<<<1, 64, 0, stream>>>(blocktot, blockoff);
  k_scanC<<<(N_NODES * NCOPY + 256) / 256, 256, 0, stream>>>(off8, blockoff);
  k_csrfill8<<<N_EDGES / 256, 256, 0, stream>>>(ei, ea, cnt8, off8, csr);
  k_degdis<<<(N_NODES + 255) / 256, 256, 0, stream>>>(off8, csr, dis, scal);
  k_pn<<<N_EDGES / 256, 256, 0, stream>>>(csr, dis);
  k_wprep<<<64, 256, 0, stream>>>(Wc1, Wl1, WT1);
  k_wprep2<<<16, 256, 0, stream>>>(Wc2, Wl2, WT2);
  k_gemm1m<<<N_NODES / 32, 256, 0, stream>>>(x, WT1, bc1, bl1, dis, hconv_f8, base1b);
  k_agg1<<<N_NODES, 256, 0, stream>>>(off8, csr, (const uint*)hconv_f8, base1b, dis, h1b);
  k_gemm2m<<<(N_NODES + 63) / 64, 256, 0, stream>>>(h1b, WT2, bc2, bl2, dis, hconv2p, base2p);
  k_agg2<<<2048, 256, 0, stream>>>(off8, csr, dis, hconv2p, base2p, out, FXbp, scal);
  k_conn<<<N_EDGES / 1024, 256, 0, stream>>>(ei, ea, FXbp, scal);
  k_finalize<<<1, 64, 0, stream>>>(scal, out + (size_t)N_NODES * KCL);
}